// Round 1
// baseline (584.738 us; speedup 1.0000x reference)
//
#include <hip/hip_runtime.h>

#define BB 4
#define HH 64
#define WW 64
#define CC 256
#define CM 128
#define OO 128
#define OFFC 54
#define OFFP 64
#define HWSZ 4096
#define NPIX 16384
#define EPSBN 1e-5f

// ---------------- pack: concat(v,i) + NCHW -> NHWC ----------------
__global__ __launch_bounds__(256) void k_pack(const float* __restrict__ v, const float* __restrict__ im,
                                              float* __restrict__ xt) {
  __shared__ float tile[32][33];
  int b = blockIdx.z;
  int hw0 = blockIdx.x * 32;
  int c0 = blockIdx.y * 32;
  int tx = threadIdx.x, ty = threadIdx.y;
#pragma unroll
  for (int i = 0; i < 32; i += 8) {
    int c = c0 + ty + i;
    const float* src = (c < CM) ? (v + ((size_t)b * CM + c) * HWSZ)
                                : (im + ((size_t)b * CM + (c - CM)) * HWSZ);
    tile[ty + i][tx] = src[hw0 + tx];
  }
  __syncthreads();
#pragma unroll
  for (int i = 0; i < 32; i += 8) {
    int hw = hw0 + ty + i;
    xt[((size_t)b * HWSZ + hw) * CC + c0 + tx] = tile[tx][ty + i];
  }
}

// ---------------- weight transposes ----------------
// w_off_t[j][OFFP], j = tap*CC + c, src off_w[o][c][tap] (tap=ky*3+kx)
__global__ __launch_bounds__(256) void k_wprep_off(const float* __restrict__ w, float* __restrict__ wt) {
  int idx = blockIdx.x * 256 + threadIdx.x;
  if (idx >= 2304 * OFFP) return;
  int o = idx & (OFFP - 1);
  int j = idx >> 6;
  int tap = j / CC, c = j % CC;
  wt[idx] = (o < OFFC) ? w[((size_t)o * CC + c) * 9 + tap] : 0.f;
}
// w_d_t[j][OO], j = k*CC + cin, src dconv_w[o][cin][k]
__global__ __launch_bounds__(256) void k_wprep_d(const float* __restrict__ w, float* __restrict__ wt) {
  int idx = blockIdx.x * 256 + threadIdx.x;
  if (idx >= 2304 * OO) return;
  int o = idx & 127;
  int j = idx >> 7;
  int k = j >> 8, cin = j & 255;
  wt[idx] = w[((size_t)o * CC + cin) * 9 + k];
}
// w_2_t[j][OO], j = tap*CM + c, src conv2_w[o][c][tap]
__global__ __launch_bounds__(256) void k_wprep_2(const float* __restrict__ w, float* __restrict__ wt) {
  int idx = blockIdx.x * 256 + threadIdx.x;
  if (idx >= 1152 * OO) return;
  int o = idx & 127;
  int j = idx >> 7;
  int tap = j / CM, c = j % CM;
  wt[idx] = w[((size_t)o * CM + c) * 9 + tap];
}

// ---------------- offset conv (3x3, 256->54pad64) + sigmoid(mask) ----------------
// block: 128 threads, tile 32 px x 64 o, 4x4 register tile
__global__ __launch_bounds__(128) void k_offconv(const float* __restrict__ xt, const float* __restrict__ wt,
                                                 const float* __restrict__ bias, float* __restrict__ off) {
  __shared__ float xs[3 * 34 * 68];
  int bid = blockIdx.x;
  int w0 = (bid & 1) * 32;
  int h = (bid >> 1) & 63;
  int b = bid >> 7;
  int t = threadIdx.x;
  int oq = t & 15, pq = t >> 4;
  float acc[4][4];
#pragma unroll
  for (int a = 0; a < 4; ++a)
#pragma unroll
    for (int bI = 0; bI < 4; ++bI) acc[a][bI] = 0.f;

  for (int cc = 0; cc < CC; cc += 64) {
    __syncthreads();
    for (int id = t; id < 3 * 34 * 64; id += 128) {
      int c = id & 63;
      int col = (id >> 6) % 34;
      int row = id / (34 * 64);
      int hh = h + row - 1;
      int ww = w0 + col - 1;
      float val = 0.f;
      if ((unsigned)hh < HH && (unsigned)ww < WW)
        val = xt[(((size_t)b * HH + hh) * WW + ww) * CC + cc + c];
      xs[(row * 34 + col) * 68 + c] = val;
    }
    __syncthreads();
#pragma unroll
    for (int tap = 0; tap < 9; ++tap) {
      const float* wrow = wt + ((size_t)(tap * CC + cc)) * OFFP;
      const float* xrow = xs + ((tap / 3) * 34 + (tap % 3)) * 68;
      for (int ci = 0; ci < 64; ci += 4) {
        float s[4][4];
#pragma unroll
        for (int pxi = 0; pxi < 4; ++pxi) {
          float4 a = *(const float4*)&xrow[(pq * 4 + pxi) * 68 + ci];
          s[pxi][0] = a.x; s[pxi][1] = a.y; s[pxi][2] = a.z; s[pxi][3] = a.w;
        }
#pragma unroll
        for (int cj = 0; cj < 4; ++cj) {
          float4 w4 = *(const float4*)&wrow[(ci + cj) * OFFP + oq * 4];
#pragma unroll
          for (int pxi = 0; pxi < 4; ++pxi) {
            acc[0][pxi] += s[pxi][cj] * w4.x;
            acc[1][pxi] += s[pxi][cj] * w4.y;
            acc[2][pxi] += s[pxi][cj] * w4.z;
            acc[3][pxi] += s[pxi][cj] * w4.w;
          }
        }
      }
    }
  }
  int pixb = (b * HH + h) * WW + w0;
#pragma unroll
  for (int oi = 0; oi < 4; ++oi) {
    int o = oq * 4 + oi;
    if (o < OFFC) {
      float bi = bias[o];
#pragma unroll
      for (int pxi = 0; pxi < 4; ++pxi) {
        float vv = acc[oi][pxi] + bi;
        if (o >= 36) vv = 1.f / (1.f + __expf(-vv));
        off[(size_t)(pixb + pq * 4 + pxi) * OFFC + o] = vv;
      }
    }
  }
}

// ---------------- deformable sample + dconv GEMM + stats ----------------
// block: 128 threads, tile 16 px x 128 o; 18 chunks of (k,g) x 128 channels
__global__ __launch_bounds__(128) void k_dconv(const float* __restrict__ xt, const float* __restrict__ off,
                                               const float* __restrict__ wt, float* __restrict__ y1p,
                                               float* __restrict__ st1, float* __restrict__ st2) {
  __shared__ unsigned int pidx[16][18][4];
  __shared__ float pwv[16][18][4];
  __shared__ float sl[16 * 132];
  int t = threadIdx.x;
  int pixb = blockIdx.x * 16;
  int b = pixb >> 12;
  int h = (pixb >> 6) & 63;
  int w0 = pixb & 63;

  for (int id = t; id < 16 * 18; id += 128) {
    int px = id / 18, gk = id % 18;
    int g = gk / 9, k = gk % 9;
    const float* op = off + (size_t)(pixb + px) * OFFC;
    float dy = op[(g * 9 + k) * 2];
    float dx = op[(g * 9 + k) * 2 + 1];
    float msk = op[36 + g * 9 + k];
    float py = dy + (float)(h + k / 3 - 1);
    float pxf = dx + (float)(w0 + px + k % 3 - 1);
    float y0f = floorf(py), x0f = floorf(pxf);
    float ly = py - y0f, lx = pxf - x0f;
    int y0 = (int)y0f, x0 = (int)x0f;
    int y1 = y0 + 1, x1 = x0 + 1;
    float oky0 = (y0 >= 0 && y0 < HH) ? 1.f : 0.f;
    float oky1 = (y1 >= 0 && y1 < HH) ? 1.f : 0.f;
    float okx0 = (x0 >= 0 && x0 < WW) ? 1.f : 0.f;
    float okx1 = (x1 >= 0 && x1 < WW) ? 1.f : 0.f;
    int y0c = min(max(y0, 0), HH - 1), y1c = min(max(y1, 0), HH - 1);
    int x0c = min(max(x0, 0), WW - 1), x1c = min(max(x1, 0), WW - 1);
    unsigned row0 = (unsigned)((b * HH + y0c) * WW);
    unsigned row1 = (unsigned)((b * HH + y1c) * WW);
    unsigned gofs = (unsigned)(g * 128);
    pidx[px][gk][0] = (row0 + x0c) * CC + gofs;
    pidx[px][gk][1] = (row0 + x1c) * CC + gofs;
    pidx[px][gk][2] = (row1 + x0c) * CC + gofs;
    pidx[px][gk][3] = (row1 + x1c) * CC + gofs;
    pwv[px][gk][0] = (1.f - ly) * (1.f - lx) * oky0 * okx0 * msk;
    pwv[px][gk][1] = (1.f - ly) * lx * oky0 * okx1 * msk;
    pwv[px][gk][2] = ly * (1.f - lx) * oky1 * okx0 * msk;
    pwv[px][gk][3] = ly * lx * oky1 * okx1 * msk;
  }

  int oq = t & 31, pq = t >> 5;
  float acc[4][4];
#pragma unroll
  for (int a = 0; a < 4; ++a)
#pragma unroll
    for (int bI = 0; bI < 4; ++bI) acc[a][bI] = 0.f;

  for (int mm = 0; mm < 18; ++mm) {
    int k = mm >> 1, g = mm & 1;
    int gk = g * 9 + k;
    __syncthreads();
#pragma unroll 4
    for (int i = 0; i < 16; ++i) {
      // px = i (uniform), c = t (coalesced)
      float vv = pwv[i][gk][0] * xt[pidx[i][gk][0] + t]
               + pwv[i][gk][1] * xt[pidx[i][gk][1] + t]
               + pwv[i][gk][2] * xt[pidx[i][gk][2] + t]
               + pwv[i][gk][3] * xt[pidx[i][gk][3] + t];
      sl[i * 132 + t] = vv;
    }
    __syncthreads();
    const float* wrow = wt + (size_t)mm * 128 * 128;
    for (int ci = 0; ci < 128; ci += 4) {
      float s[4][4];
#pragma unroll
      for (int pxi = 0; pxi < 4; ++pxi) {
        float4 a = *(const float4*)&sl[(pq * 4 + pxi) * 132 + ci];
        s[pxi][0] = a.x; s[pxi][1] = a.y; s[pxi][2] = a.z; s[pxi][3] = a.w;
      }
#pragma unroll
      for (int cj = 0; cj < 4; ++cj) {
        float4 w4 = *(const float4*)&wrow[(ci + cj) * 128 + oq * 4];
#pragma unroll
        for (int pxi = 0; pxi < 4; ++pxi) {
          acc[0][pxi] += s[pxi][cj] * w4.x;
          acc[1][pxi] += s[pxi][cj] * w4.y;
          acc[2][pxi] += s[pxi][cj] * w4.z;
          acc[3][pxi] += s[pxi][cj] * w4.w;
        }
      }
    }
  }

  // epilogue: write pre-BN + stats
#pragma unroll
  for (int pxi = 0; pxi < 4; ++pxi) {
    float4 st = make_float4(acc[0][pxi], acc[1][pxi], acc[2][pxi], acc[3][pxi]);
    *(float4*)&y1p[(size_t)(pixb + pq * 4 + pxi) * OO + oq * 4] = st;
  }
  float s1[4], s2[4];
#pragma unroll
  for (int oi = 0; oi < 4; ++oi) {
    s1[oi] = 0.f; s2[oi] = 0.f;
#pragma unroll
    for (int pxi = 0; pxi < 4; ++pxi) {
      float vv = acc[oi][pxi];
      s1[oi] += vv; s2[oi] += vv * vv;
    }
  }
  __syncthreads();
  float* red = sl;
#pragma unroll
  for (int oi = 0; oi < 4; ++oi) {
    int o = oq * 4 + oi;
    red[pq * 128 + o] = s1[oi];
    red[512 + pq * 128 + o] = s2[oi];
  }
  __syncthreads();
  float a1 = red[t] + red[128 + t] + red[256 + t] + red[384 + t];
  float a2 = red[512 + t] + red[640 + t] + red[768 + t] + red[896 + t];
  atomicAdd(&st1[t], a1);
  atomicAdd(&st2[t], a2);
}

// ---------------- bn1 + relu (elementwise, NHWC) ----------------
__global__ __launch_bounds__(256) void k_bnrelu1(const float* __restrict__ yp, const float* __restrict__ s1,
                                                 const float* __restrict__ s2, const float* __restrict__ g,
                                                 const float* __restrict__ bb, float* __restrict__ y) {
  __shared__ float sc[128], sh[128];
  int t = threadIdx.x;
  if (t < 128) {
    float m = s1[t] * (1.f / 16384.f);
    float var = s2[t] * (1.f / 16384.f) - m * m;
    float s = g[t] * rsqrtf(var + EPSBN);
    sc[t] = s;
    sh[t] = bb[t] - m * s;
  }
  __syncthreads();
  size_t i = (size_t)blockIdx.x * 256 + t;
  float4 v = ((const float4*)yp)[i];
  int c0 = (int)((i * 4) & 127);
  v.x = fmaxf(0.f, v.x * sc[c0] + sh[c0]);
  v.y = fmaxf(0.f, v.y * sc[c0 + 1] + sh[c0 + 1]);
  v.z = fmaxf(0.f, v.z * sc[c0 + 2] + sh[c0 + 2]);
  v.w = fmaxf(0.f, v.w * sc[c0 + 3] + sh[c0 + 3]);
  ((float4*)y)[i] = v;
}

// ---------------- conv2 (3x3, 128->128) + stats ----------------
__global__ __launch_bounds__(128) void k_conv2(const float* __restrict__ y1, const float* __restrict__ wt,
                                               float* __restrict__ y2p, float* __restrict__ st1,
                                               float* __restrict__ st2) {
  __shared__ float xs[3 * 18 * 68];
  int pixb = blockIdx.x * 16;
  int b = pixb >> 12, h = (pixb >> 6) & 63, w0 = pixb & 63;
  int t = threadIdx.x;
  int oq = t & 31, pq = t >> 5;
  float acc[4][4];
#pragma unroll
  for (int a = 0; a < 4; ++a)
#pragma unroll
    for (int bI = 0; bI < 4; ++bI) acc[a][bI] = 0.f;

  for (int cc = 0; cc < CM; cc += 64) {
    __syncthreads();
    for (int id = t; id < 3 * 18 * 64; id += 128) {
      int c = id & 63;
      int col = (id >> 6) % 18;
      int row = id / (18 * 64);
      int hh = h + row - 1;
      int ww = w0 + col - 1;
      float val = 0.f;
      if ((unsigned)hh < HH && (unsigned)ww < WW)
        val = y1[(((size_t)b * HH + hh) * WW + ww) * CM + cc + c];
      xs[(row * 18 + col) * 68 + c] = val;
    }
    __syncthreads();
#pragma unroll
    for (int tap = 0; tap < 9; ++tap) {
      const float* wrow = wt + ((size_t)(tap * CM + cc)) * OO;
      const float* xrow = xs + ((tap / 3) * 18 + (tap % 3)) * 68;
      for (int ci = 0; ci < 64; ci += 4) {
        float s[4][4];
#pragma unroll
        for (int pxi = 0; pxi < 4; ++pxi) {
          float4 a = *(const float4*)&xrow[(pq * 4 + pxi) * 68 + ci];
          s[pxi][0] = a.x; s[pxi][1] = a.y; s[pxi][2] = a.z; s[pxi][3] = a.w;
        }
#pragma unroll
        for (int cj = 0; cj < 4; ++cj) {
          float4 w4 = *(const float4*)&wrow[(ci + cj) * OO + oq * 4];
#pragma unroll
          for (int pxi = 0; pxi < 4; ++pxi) {
            acc[0][pxi] += s[pxi][cj] * w4.x;
            acc[1][pxi] += s[pxi][cj] * w4.y;
            acc[2][pxi] += s[pxi][cj] * w4.z;
            acc[3][pxi] += s[pxi][cj] * w4.w;
          }
        }
      }
    }
  }
#pragma unroll
  for (int pxi = 0; pxi < 4; ++pxi) {
    float4 st = make_float4(acc[0][pxi], acc[1][pxi], acc[2][pxi], acc[3][pxi]);
    *(float4*)&y2p[(size_t)(pixb + pq * 4 + pxi) * OO + oq * 4] = st;
  }
  float s1[4], s2[4];
#pragma unroll
  for (int oi = 0; oi < 4; ++oi) {
    s1[oi] = 0.f; s2[oi] = 0.f;
#pragma unroll
    for (int pxi = 0; pxi < 4; ++pxi) {
      float vv = acc[oi][pxi];
      s1[oi] += vv; s2[oi] += vv * vv;
    }
  }
  __syncthreads();
  float* red = xs;
#pragma unroll
  for (int oi = 0; oi < 4; ++oi) {
    int o = oq * 4 + oi;
    red[pq * 128 + o] = s1[oi];
    red[512 + pq * 128 + o] = s2[oi];
  }
  __syncthreads();
  float a1 = red[t] + red[128 + t] + red[256 + t] + red[384 + t];
  float a2 = red[512 + t] + red[640 + t] + red[768 + t] + red[896 + t];
  atomicAdd(&st1[t], a1);
  atomicAdd(&st2[t], a2);
}

// ---------------- bn2 + relu + NHWC -> NCHW ----------------
__global__ __launch_bounds__(256) void k_bnrelu2(const float* __restrict__ yp, const float* __restrict__ s1,
                                                 const float* __restrict__ s2, const float* __restrict__ g,
                                                 const float* __restrict__ bb, float* __restrict__ out) {
  __shared__ float sc[128], sh[128];
  int t = threadIdx.x;
  if (t < 128) {
    float m = s1[t] * (1.f / 16384.f);
    float var = s2[t] * (1.f / 16384.f) - m * m;
    float s = g[t] * rsqrtf(var + EPSBN);
    sc[t] = s;
    sh[t] = bb[t] - m * s;
  }
  __syncthreads();
  int bh = blockIdx.x;
  int b = bh >> 6, h = bh & 63;
  const float* src = yp + (size_t)bh * 64 * 128;
  for (int id = t; id < 64 * 128; id += 256) {
    int w = id & 63, o = id >> 6;
    float v = src[w * 128 + o];
    v = fmaxf(0.f, v * sc[o] + sh[o]);
    out[(((size_t)b * OO + o) * HH + h) * WW + w] = v;
  }
}

extern "C" void kernel_launch(void* const* d_in, const int* in_sizes, int n_in,
                              void* d_out, int out_size, void* d_ws, size_t ws_size,
                              hipStream_t stream) {
  const float* in_v = (const float*)d_in[0];
  const float* in_i = (const float*)d_in[1];
  const float* off_w = (const float*)d_in[2];
  const float* off_b = (const float*)d_in[3];
  const float* dconv_w = (const float*)d_in[4];
  const float* bn1_g = (const float*)d_in[5];
  const float* bn1_b = (const float*)d_in[6];
  const float* conv2_w = (const float*)d_in[7];
  const float* bn2_g = (const float*)d_in[8];
  const float* bn2_b = (const float*)d_in[9];
  float* out = (float*)d_out;

  char* w = (char*)d_ws;
  float* x_nhwc = (float*)w;   w += (size_t)NPIX * CC * 4;
  float* off_nhwc = (float*)w; w += (size_t)NPIX * OFFC * 4;
  float* w_off_t = (float*)w;  w += (size_t)2304 * OFFP * 4;
  float* w_d_t = (float*)w;    w += (size_t)2304 * OO * 4;
  float* w_2_t = (float*)w;    w += (size_t)1152 * OO * 4;
  float* y1p = (float*)w;      w += (size_t)NPIX * OO * 4;
  float* y1 = (float*)w;       w += (size_t)NPIX * OO * 4;
  float* stats = (float*)w;    w += (size_t)4 * 128 * 4;
  float* y2p = y1p;  // reuse: y1p dead after bnrelu1

  hipMemsetAsync(stats, 0, 4 * 128 * 4, stream);
  k_pack<<<dim3(128, 8, 4), dim3(32, 8, 1), 0, stream>>>(in_v, in_i, x_nhwc);
  k_wprep_off<<<576, 256, 0, stream>>>(off_w, w_off_t);
  k_wprep_d<<<1152, 256, 0, stream>>>(dconv_w, w_d_t);
  k_wprep_2<<<576, 256, 0, stream>>>(conv2_w, w_2_t);
  k_offconv<<<512, 128, 0, stream>>>(x_nhwc, w_off_t, off_b, off_nhwc);
  k_dconv<<<1024, 128, 0, stream>>>(x_nhwc, off_nhwc, w_d_t, y1p, stats, stats + 128);
  k_bnrelu1<<<2048, 256, 0, stream>>>(y1p, stats, stats + 128, bn1_g, bn1_b, y1);
  k_conv2<<<1024, 128, 0, stream>>>(y1, w_2_t, y2p, stats + 256, stats + 384);
  k_bnrelu2<<<256, 256, 0, stream>>>(y2p, stats + 256, stats + 384, bn2_g, bn2_b, out);
}

// Round 2
// 234.757 us; speedup vs baseline: 2.4908x; 2.4908x over previous
//
#include <hip/hip_runtime.h>

#define EPSBN 1e-5f

using s8v = __attribute__((ext_vector_type(8))) short;
using f4v = __attribute__((ext_vector_type(4))) float;

__device__ inline unsigned short f2bf(float f) {
  unsigned u = __float_as_uint(f);
  return (unsigned short)((u + 0x7FFFu + ((u >> 16) & 1u)) >> 16);
}
__device__ inline float bf2f(unsigned short h) {
  return __uint_as_float(((unsigned)h) << 16);
}

// ---------------- pack: concat(v,i) + NCHW f32 -> NHWC bf16 ----------------
__global__ __launch_bounds__(256) void k_pack(const float* __restrict__ v, const float* __restrict__ im,
                                              unsigned short* __restrict__ xb) {
  __shared__ float tile[64][33];
  int b = blockIdx.z;
  int hw0 = blockIdx.x * 32;
  int c0 = blockIdx.y * 64;
  int tx = threadIdx.x, ty = threadIdx.y;
#pragma unroll
  for (int i = 0; i < 64; i += 8) {
    int c = c0 + ty + i;
    const float* src = (c < 128) ? (v + ((size_t)b * 128 + c) * 4096)
                                 : (im + ((size_t)b * 128 + (c - 128)) * 4096);
    tile[ty + i][tx] = src[hw0 + tx];
  }
  __syncthreads();
#pragma unroll
  for (int i = 0; i < 32; i += 8) {
    int hw = hw0 + ty + i;
    ushort2 o;
    o.x = f2bf(tile[2 * tx][ty + i]);
    o.y = f2bf(tile[2 * tx + 1][ty + i]);
    *(ushort2*)&xb[((size_t)(b * 4096 + hw)) * 256 + c0 + 2 * tx] = o;
  }
}

// ---------------- weight prep: fragment-major bf16 ----------------
// k-convention (self-consistent A/B): within a 32-K step, k = (lane>>4)*8 + j
// offconv: kstep = (cc*9+tap)*2+ks2 ; c = cc*64 + ks2*32 + k ; N=64 (o<54 real)
__global__ __launch_bounds__(256) void k_wprep_off(const float* __restrict__ w, unsigned short* __restrict__ wt) {
  int id = blockIdx.x * 256 + threadIdx.x;  // 72*4*64 = 18432
  int lane = id & 63;
  int nb = (id >> 6) & 3;
  int ks = id >> 8;  // 0..71
  int ks2 = ks & 1, tap = (ks >> 1) % 9, cc = ks / 18;
  int o = nb * 16 + (lane & 15);
  int cb = cc * 64 + ks2 * 32 + ((lane >> 4) * 8);
  s8v r;
#pragma unroll
  for (int j = 0; j < 8; ++j) {
    float val = (o < 54) ? w[((size_t)o * 256 + cb + j) * 9 + tap] : 0.f;
    r[j] = (short)f2bf(val);
  }
  *(s8v*)&wt[(size_t)id * 8] = r;
}
// dconv: chunk = g*9+kk (18), kstep = chunk*4+ks4 ; cin = g*128 + ks4*32 + k ; N=128
__global__ __launch_bounds__(256) void k_wprep_d(const float* __restrict__ w, unsigned short* __restrict__ wt) {
  int id = blockIdx.x * 256 + threadIdx.x;  // 72*8*64 = 36864
  int lane = id & 63;
  int nb = (id >> 6) & 7;
  int kstep = id >> 9;  // 0..71
  int chunk = kstep >> 2, ks4 = kstep & 3;
  int g = chunk / 9, kk = chunk % 9;
  int o = nb * 16 + (lane & 15);
  int cb = g * 128 + ks4 * 32 + ((lane >> 4) * 8);
  s8v r;
#pragma unroll
  for (int j = 0; j < 8; ++j) r[j] = (short)f2bf(w[((size_t)o * 256 + cb + j) * 9 + kk]);
  *(s8v*)&wt[(size_t)id * 8] = r;
}
// conv2: kstep = (cc*9+tap)*2+ks2 (36) ; c = cc*64 + ks2*32 + k ; N=128, Cin=128
__global__ __launch_bounds__(256) void k_wprep_2(const float* __restrict__ w, unsigned short* __restrict__ wt) {
  int id = blockIdx.x * 256 + threadIdx.x;  // 36*8*64 = 18432
  int lane = id & 63;
  int nb = (id >> 6) & 7;
  int kstep = id >> 9;  // 0..35
  int ks2 = kstep & 1, tap = (kstep >> 1) % 9, cc = kstep / 18;
  int o = nb * 16 + (lane & 15);
  int cb = cc * 64 + ks2 * 32 + ((lane >> 4) * 8);
  s8v r;
#pragma unroll
  for (int j = 0; j < 8; ++j) r[j] = (short)f2bf(w[((size_t)o * 128 + cb + j) * 9 + tap]);
  *(s8v*)&wt[(size_t)id * 8] = r;
}

// ---------------- offset conv: MFMA, block = 32px x 64o, 4 waves (16px x 32o) ----------------
__global__ __launch_bounds__(256) void k_offconv(const unsigned short* __restrict__ xb,
                                                 const unsigned short* __restrict__ wt,
                                                 const float* __restrict__ bias,
                                                 float* __restrict__ off) {
  __shared__ char As[102 * 128];  // [3*34 rows][64 ch] bf16, XOR-swizzled
  int bid = blockIdx.x;
  int w0 = (bid & 1) * 32;
  int h = (bid >> 1) & 63;
  int b = bid >> 7;
  int t = threadIdx.x;
  int l = t & 63, wv = t >> 6;
  int pxg = wv >> 1, og = wv & 1;
  f4v zero = {0.f, 0.f, 0.f, 0.f};
  f4v acc[2] = {zero, zero};

  for (int cc = 0; cc < 4; ++cc) {
    __syncthreads();
    for (int id = t; id < 816; id += 256) {
      int tr = id >> 3, o8 = id & 7;
      int ky = tr / 34, col = tr % 34;
      int hh = h + ky - 1, ww = w0 + col - 1;
      s8v val = {0, 0, 0, 0, 0, 0, 0, 0};
      if ((unsigned)hh < 64u && (unsigned)ww < 64u)
        val = *(const s8v*)&xb[(((size_t)(b * 64 + hh)) * 64 + ww) * 256 + cc * 64 + o8 * 8];
      int byte = (tr * 128 + o8 * 16) ^ ((tr & 7) << 4);
      *(s8v*)(As + byte) = val;
    }
    __syncthreads();
#pragma unroll
    for (int tap = 0; tap < 9; ++tap) {
      int ky = tap / 3, kx = tap % 3;
      int tr = ky * 34 + pxg * 16 + (l & 15) + kx;
#pragma unroll
      for (int ks2 = 0; ks2 < 2; ++ks2) {
        int byte = (tr * 128 + (ks2 * 32 + (l >> 4) * 8) * 2) ^ ((tr & 7) << 4);
        s8v a = *(const s8v*)(As + byte);
        int kstep = (cc * 9 + tap) * 2 + ks2;
#pragma unroll
        for (int nf = 0; nf < 2; ++nf) {
          int nb = og * 2 + nf;
          s8v bfr = *(const s8v*)&wt[(((size_t)kstep * 4 + nb) * 64 + l) * 8];
          acc[nf] = __builtin_amdgcn_mfma_f32_16x16x32_bf16(a, bfr, acc[nf], 0, 0, 0);
        }
      }
    }
  }
  int pixb = (b * 64 + h) * 64 + w0;
#pragma unroll
  for (int nf = 0; nf < 2; ++nf) {
    int o = og * 32 + nf * 16 + (l & 15);
    if (o < 54) {
      float bi = bias[o];
#pragma unroll
      for (int j = 0; j < 4; ++j) {
        int px = pixb + pxg * 16 + (l >> 4) * 4 + j;
        float vv = acc[nf][j] + bi;
        if (o >= 36) vv = 1.f / (1.f + __expf(-vv));
        off[(size_t)px * 54 + o] = vv;
      }
    }
  }
}

// ---------------- deform sample + dconv: MFMA, block = 32px x 128o ----------------
__global__ __launch_bounds__(256) void k_dconv(const unsigned short* __restrict__ xb,
                                               const float* __restrict__ off,
                                               const unsigned short* __restrict__ wt,
                                               float* __restrict__ y1p) {
  __shared__ unsigned int sidx[18][32][4];
  __shared__ float swt[18][32][4];
  __shared__ char At[32 * 256];  // [32px][128 ch] bf16, XOR-swizzled
  int t = threadIdx.x;
  int l = t & 63, wv = t >> 6;
  int pxg = wv >> 1, og = wv & 1;
  int pixb = blockIdx.x * 32;
  int b = pixb >> 12, h = (pixb >> 6) & 63, w0 = pixb & 63;

  for (int id = t; id < 576; id += 256) {
    int chunk = id >> 5, px = id & 31;
    int g = chunk / 9, kk = chunk % 9;
    const float* op = off + (size_t)(pixb + px) * 54;
    float dy = op[(g * 9 + kk) * 2];
    float dx = op[(g * 9 + kk) * 2 + 1];
    float msk = op[36 + g * 9 + kk];
    float py = dy + (float)(h + kk / 3 - 1);
    float pxf = dx + (float)(w0 + px + kk % 3 - 1);
    float y0f = floorf(py), x0f = floorf(pxf);
    float ly = py - y0f, lx = pxf - x0f;
    int y0 = (int)y0f, x0 = (int)x0f;
    int y1 = y0 + 1, x1 = x0 + 1;
    float oky0 = (y0 >= 0 && y0 < 64) ? 1.f : 0.f;
    float oky1 = (y1 >= 0 && y1 < 64) ? 1.f : 0.f;
    float okx0 = (x0 >= 0 && x0 < 64) ? 1.f : 0.f;
    float okx1 = (x1 >= 0 && x1 < 64) ? 1.f : 0.f;
    int y0c = min(max(y0, 0), 63), y1c = min(max(y1, 0), 63);
    int x0c = min(max(x0, 0), 63), x1c = min(max(x1, 0), 63);
    unsigned base = (unsigned)(b * 4096);
    unsigned gofs = (unsigned)(g * 128);
    sidx[chunk][px][0] = (base + y0c * 64 + x0c) * 256u + gofs;
    sidx[chunk][px][1] = (base + y0c * 64 + x1c) * 256u + gofs;
    sidx[chunk][px][2] = (base + y1c * 64 + x0c) * 256u + gofs;
    sidx[chunk][px][3] = (base + y1c * 64 + x1c) * 256u + gofs;
    swt[chunk][px][0] = (1.f - ly) * (1.f - lx) * oky0 * okx0 * msk;
    swt[chunk][px][1] = (1.f - ly) * lx * oky0 * okx1 * msk;
    swt[chunk][px][2] = ly * (1.f - lx) * oky1 * okx0 * msk;
    swt[chunk][px][3] = ly * lx * oky1 * okx1 * msk;
  }

  f4v zero = {0.f, 0.f, 0.f, 0.f};
  f4v acc[4] = {zero, zero, zero, zero};

  for (int chunk = 0; chunk < 18; ++chunk) {
    __syncthreads();
    {
      int px = t >> 3, o8 = t & 7;
      unsigned i0 = sidx[chunk][px][0], i1 = sidx[chunk][px][1];
      unsigned i2 = sidx[chunk][px][2], i3 = sidx[chunk][px][3];
      float q0 = swt[chunk][px][0], q1 = swt[chunk][px][1];
      float q2 = swt[chunk][px][2], q3 = swt[chunk][px][3];
#pragma unroll
      for (int half = 0; half < 2; ++half) {
        int choff = o8 * 16 + half * 8;
        s8v v0 = *(const s8v*)&xb[i0 + choff];
        s8v v1 = *(const s8v*)&xb[i1 + choff];
        s8v v2 = *(const s8v*)&xb[i2 + choff];
        s8v v3 = *(const s8v*)&xb[i3 + choff];
        s8v r;
#pragma unroll
        for (int j = 0; j < 8; ++j) {
          float f = q0 * bf2f((unsigned short)v0[j]) + q1 * bf2f((unsigned short)v1[j]) +
                    q2 * bf2f((unsigned short)v2[j]) + q3 * bf2f((unsigned short)v3[j]);
          r[j] = (short)f2bf(f);
        }
        int byte = (px * 256 + choff * 2) ^ ((px & 7) << 4);
        *(s8v*)(At + byte) = r;
      }
    }
    __syncthreads();
#pragma unroll
    for (int ks4 = 0; ks4 < 4; ++ks4) {
      int tr = pxg * 16 + (l & 15);
      int byte = (tr * 256 + (ks4 * 32 + (l >> 4) * 8) * 2) ^ ((tr & 7) << 4);
      s8v a = *(const s8v*)(At + byte);
      int kstep = chunk * 4 + ks4;
#pragma unroll
      for (int nf = 0; nf < 4; ++nf) {
        int nb = og * 4 + nf;
        s8v bfr = *(const s8v*)&wt[(((size_t)kstep * 8 + nb) * 64 + l) * 8];
        acc[nf] = __builtin_amdgcn_mfma_f32_16x16x32_bf16(a, bfr, acc[nf], 0, 0, 0);
      }
    }
  }
#pragma unroll
  for (int nf = 0; nf < 4; ++nf) {
    int o = og * 64 + nf * 16 + (l & 15);
#pragma unroll
    for (int j = 0; j < 4; ++j) {
      int px = pixb + pxg * 16 + (l >> 4) * 4 + j;
      y1p[(size_t)px * 128 + o] = acc[nf][j];
    }
  }
}

// ---------------- per-channel stats (sum, sumsq) over [16384][128] ----------------
__global__ __launch_bounds__(256) void k_stats(const float* __restrict__ y, float* __restrict__ s1,
                                               float* __restrict__ s2) {
  __shared__ float red[2][8][128];
  int t = threadIdx.x;
  int q = t & 31, pg = t >> 5;
  float a[4] = {0.f, 0.f, 0.f, 0.f}, bsq[4] = {0.f, 0.f, 0.f, 0.f};
  int px0 = blockIdx.x * 256 + pg * 32;
  for (int i = 0; i < 32; ++i) {
    float4 v = *(const float4*)&y[((size_t)(px0 + i)) * 128 + q * 4];
    a[0] += v.x; a[1] += v.y; a[2] += v.z; a[3] += v.w;
    bsq[0] += v.x * v.x; bsq[1] += v.y * v.y; bsq[2] += v.z * v.z; bsq[3] += v.w * v.w;
  }
#pragma unroll
  for (int k2 = 0; k2 < 4; ++k2) {
    red[0][pg][q * 4 + k2] = a[k2];
    red[1][pg][q * 4 + k2] = bsq[k2];
  }
  __syncthreads();
  if (t < 128) {
    float x1 = 0.f, x2 = 0.f;
#pragma unroll
    for (int p = 0; p < 8; ++p) { x1 += red[0][p][t]; x2 += red[1][p][t]; }
    atomicAdd(&s1[t], x1);
    atomicAdd(&s2[t], x2);
  }
}

// ---------------- conv2: MFMA, bn1+relu fused into A-staging ----------------
__global__ __launch_bounds__(256) void k_conv2(const float* __restrict__ y1p,
                                               const unsigned short* __restrict__ wt,
                                               const float* __restrict__ st1, const float* __restrict__ st2,
                                               const float* __restrict__ g1, const float* __restrict__ b1,
                                               float* __restrict__ y2p) {
  __shared__ char As[102 * 128];
  __shared__ float scs[128], shs[128];
  int bid = blockIdx.x;
  int w0 = (bid & 1) * 32;
  int h = (bid >> 1) & 63;
  int b = bid >> 7;
  int t = threadIdx.x;
  int l = t & 63, wv = t >> 6;
  int pxg = wv >> 1, og = wv & 1;
  if (t < 128) {
    float m = st1[t] * (1.f / 16384.f);
    float var = st2[t] * (1.f / 16384.f) - m * m;
    float s = g1[t] * rsqrtf(var + EPSBN);
    scs[t] = s;
    shs[t] = b1[t] - m * s;
  }
  f4v zero = {0.f, 0.f, 0.f, 0.f};
  f4v acc[4] = {zero, zero, zero, zero};

  for (int cc = 0; cc < 2; ++cc) {
    __syncthreads();
    for (int id = t; id < 816; id += 256) {
      int tr = id >> 3, o8 = id & 7;
      int ky = tr / 34, col = tr % 34;
      int hh = h + ky - 1, ww = w0 + col - 1;
      s8v r = {0, 0, 0, 0, 0, 0, 0, 0};
      if ((unsigned)hh < 64u && (unsigned)ww < 64u) {
        const float* src = y1p + (((size_t)(b * 64 + hh)) * 64 + ww) * 128 + cc * 64 + o8 * 8;
#pragma unroll
        for (int j = 0; j < 8; ++j) {
          int c = cc * 64 + o8 * 8 + j;
          float f = fmaxf(0.f, src[j] * scs[c] + shs[c]);
          r[j] = (short)f2bf(f);
        }
      }
      int byte = (tr * 128 + o8 * 16) ^ ((tr & 7) << 4);
      *(s8v*)(As + byte) = r;
    }
    __syncthreads();
#pragma unroll
    for (int tap = 0; tap < 9; ++tap) {
      int ky = tap / 3, kx = tap % 3;
      int tr = ky * 34 + pxg * 16 + (l & 15) + kx;
#pragma unroll
      for (int ks2 = 0; ks2 < 2; ++ks2) {
        int byte = (tr * 128 + (ks2 * 32 + (l >> 4) * 8) * 2) ^ ((tr & 7) << 4);
        s8v a = *(const s8v*)(As + byte);
        int kstep = (cc * 9 + tap) * 2 + ks2;
#pragma unroll
        for (int nf = 0; nf < 4; ++nf) {
          int nb = og * 4 + nf;
          s8v bfr = *(const s8v*)&wt[(((size_t)kstep * 8 + nb) * 64 + l) * 8];
          acc[nf] = __builtin_amdgcn_mfma_f32_16x16x32_bf16(a, bfr, acc[nf], 0, 0, 0);
        }
      }
    }
  }
  int pixb = (b * 64 + h) * 64 + w0;
#pragma unroll
  for (int nf = 0; nf < 4; ++nf) {
    int o = og * 64 + nf * 16 + (l & 15);
#pragma unroll
    for (int j = 0; j < 4; ++j) {
      int px = pixb + pxg * 16 + (l >> 4) * 4 + j;
      y2p[(size_t)px * 128 + o] = acc[nf][j];
    }
  }
}

// ---------------- bn2 + relu + NHWC -> NCHW ----------------
__global__ __launch_bounds__(256) void k_bnrelu2(const float* __restrict__ yp, const float* __restrict__ s1,
                                                 const float* __restrict__ s2, const float* __restrict__ g,
                                                 const float* __restrict__ bb, float* __restrict__ out) {
  __shared__ float sc[128], sh[128];
  int t = threadIdx.x;
  if (t < 128) {
    float m = s1[t] * (1.f / 16384.f);
    float var = s2[t] * (1.f / 16384.f) - m * m;
    float s = g[t] * rsqrtf(var + EPSBN);
    sc[t] = s;
    sh[t] = bb[t] - m * s;
  }
  __syncthreads();
  int bh = blockIdx.x;
  int b = bh >> 6, h = bh & 63;
  const float* src = yp + (size_t)bh * 64 * 128;
  for (int id = t; id < 64 * 128; id += 256) {
    int w = id & 63, o = id >> 6;
    float v = src[w * 128 + o];
    v = fmaxf(0.f, v * sc[o] + sh[o]);
    out[(((size_t)b * 128 + o) * 64 + h) * 64 + w] = v;
  }
}

extern "C" void kernel_launch(void* const* d_in, const int* in_sizes, int n_in,
                              void* d_out, int out_size, void* d_ws, size_t ws_size,
                              hipStream_t stream) {
  const float* in_v = (const float*)d_in[0];
  const float* in_i = (const float*)d_in[1];
  const float* off_w = (const float*)d_in[2];
  const float* off_b = (const float*)d_in[3];
  const float* dconv_w = (const float*)d_in[4];
  const float* bn1_g = (const float*)d_in[5];
  const float* bn1_b = (const float*)d_in[6];
  const float* conv2_w = (const float*)d_in[7];
  const float* bn2_g = (const float*)d_in[8];
  const float* bn2_b = (const float*)d_in[9];
  float* out = (float*)d_out;

  char* w = (char*)d_ws;
  unsigned short* xb = (unsigned short*)w;   w += (size_t)16384 * 256 * 2;   // 8 MB
  float* off_nhwc = (float*)w;               w += (size_t)16384 * 54 * 4;    // 3.4 MB
  unsigned short* wtf_off = (unsigned short*)w; w += (size_t)18432 * 8 * 2;  // 288 KB
  unsigned short* wtf_d = (unsigned short*)w;   w += (size_t)36864 * 8 * 2;  // 576 KB
  unsigned short* wtf_2 = (unsigned short*)w;   w += (size_t)18432 * 8 * 2;  // 288 KB
  float* y1p = (float*)w;                    w += (size_t)16384 * 128 * 4;   // 8 MB
  float* y2p = (float*)w;                    w += (size_t)16384 * 128 * 4;   // 8 MB
  float* stats = (float*)w;                  w += 512 * 4;

  hipMemsetAsync(stats, 0, 512 * 4, stream);
  k_pack<<<dim3(128, 4, 4), dim3(32, 8), 0, stream>>>(in_v, in_i, xb);
  k_wprep_off<<<72, 256, 0, stream>>>(off_w, wtf_off);
  k_wprep_d<<<144, 256, 0, stream>>>(dconv_w, wtf_d);
  k_wprep_2<<<72, 256, 0, stream>>>(conv2_w, wtf_2);
  k_offconv<<<512, 256, 0, stream>>>(xb, wtf_off, off_b, off_nhwc);
  k_dconv<<<512, 256, 0, stream>>>(xb, off_nhwc, wtf_d, y1p);
  k_stats<<<64, 256, 0, stream>>>(y1p, stats, stats + 128);
  k_conv2<<<512, 256, 0, stream>>>(y1p, wtf_2, stats, stats + 128, bn1_g, bn1_b, y2p);
  k_stats<<<64, 256, 0, stream>>>(y2p, stats + 256, stats + 384);
  k_bnrelu2<<<256, 256, 0, stream>>>(y2p, stats + 256, stats + 384, bn2_g, bn2_b, out);
}

// Round 3
// 179.875 us; speedup vs baseline: 3.2508x; 1.3051x over previous
//
#include <hip/hip_runtime.h>

#define EPSBN 1e-5f

using s8v = __attribute__((ext_vector_type(8))) short;
using f4v = __attribute__((ext_vector_type(4))) float;

__device__ inline unsigned short f2bf(float f) {
  unsigned u = __float_as_uint(f);
  return (unsigned short)((u + 0x7FFFu + ((u >> 16) & 1u)) >> 16);
}
__device__ inline float bf2f(unsigned short h) {
  return __uint_as_float(((unsigned)h) << 16);
}

// ---------------- pack: concat(v,i) + NCHW f32 -> NHWC bf16 ----------------
__global__ __launch_bounds__(256) void k_pack(const float* __restrict__ v, const float* __restrict__ im,
                                              unsigned short* __restrict__ xb) {
  __shared__ float tile[64][33];
  int b = blockIdx.z;
  int hw0 = blockIdx.x * 32;
  int c0 = blockIdx.y * 64;
  int tx = threadIdx.x, ty = threadIdx.y;
#pragma unroll
  for (int i = 0; i < 64; i += 8) {
    int c = c0 + ty + i;
    const float* src = (c < 128) ? (v + ((size_t)b * 128 + c) * 4096)
                                 : (im + ((size_t)b * 128 + (c - 128)) * 4096);
    tile[ty + i][tx] = src[hw0 + tx];
  }
  __syncthreads();
#pragma unroll
  for (int i = 0; i < 32; i += 8) {
    int hw = hw0 + ty + i;
    ushort2 o;
    o.x = f2bf(tile[2 * tx][ty + i]);
    o.y = f2bf(tile[2 * tx + 1][ty + i]);
    *(ushort2*)&xb[((size_t)(b * 4096 + hw)) * 256 + c0 + 2 * tx] = o;
  }
}

// ---------------- weight prep: fragment-major bf16 (unchanged, verified) ----------------
__global__ __launch_bounds__(256) void k_wprep_off(const float* __restrict__ w, unsigned short* __restrict__ wt) {
  int id = blockIdx.x * 256 + threadIdx.x;  // 72*4*64 = 18432
  int lane = id & 63;
  int nb = (id >> 6) & 3;
  int ks = id >> 8;
  int ks2 = ks & 1, tap = (ks >> 1) % 9, cc = ks / 18;
  int o = nb * 16 + (lane & 15);
  int cb = cc * 64 + ks2 * 32 + ((lane >> 4) * 8);
  s8v r;
#pragma unroll
  for (int j = 0; j < 8; ++j) {
    float val = (o < 54) ? w[((size_t)o * 256 + cb + j) * 9 + tap] : 0.f;
    r[j] = (short)f2bf(val);
  }
  *(s8v*)&wt[(size_t)id * 8] = r;
}
__global__ __launch_bounds__(256) void k_wprep_d(const float* __restrict__ w, unsigned short* __restrict__ wt) {
  int id = blockIdx.x * 256 + threadIdx.x;  // 72*8*64 = 36864
  int lane = id & 63;
  int nb = (id >> 6) & 7;
  int kstep = id >> 9;
  int chunk = kstep >> 2, ks4 = kstep & 3;
  int g = chunk / 9, kk = chunk % 9;
  int o = nb * 16 + (lane & 15);
  int cb = g * 128 + ks4 * 32 + ((lane >> 4) * 8);
  s8v r;
#pragma unroll
  for (int j = 0; j < 8; ++j) r[j] = (short)f2bf(w[((size_t)o * 256 + cb + j) * 9 + kk]);
  *(s8v*)&wt[(size_t)id * 8] = r;
}
__global__ __launch_bounds__(256) void k_wprep_2(const float* __restrict__ w, unsigned short* __restrict__ wt) {
  int id = blockIdx.x * 256 + threadIdx.x;  // 36*8*64 = 18432
  int lane = id & 63;
  int nb = (id >> 6) & 7;
  int kstep = id >> 9;
  int ks2 = kstep & 1, tap = (kstep >> 1) % 9, cc = kstep / 18;
  int o = nb * 16 + (lane & 15);
  int cb = cc * 64 + ks2 * 32 + ((lane >> 4) * 8);
  s8v r;
#pragma unroll
  for (int j = 0; j < 8; ++j) r[j] = (short)f2bf(w[((size_t)o * 128 + cb + j) * 9 + tap]);
  *(s8v*)&wt[(size_t)id * 8] = r;
}

// ---------------- offset conv: 512 thr, single-stage LDS, 2 barriers ----------------
__global__ __launch_bounds__(512, 4) void k_offconv(const unsigned short* __restrict__ xb,
                                                    const unsigned short* __restrict__ wt,
                                                    const float* __restrict__ bias,
                                                    float* __restrict__ off) {
  __shared__ char Xs[102 * 512];  // [3*34 rows][256 ch] bf16, XOR-swizzled
  int bid = blockIdx.x;
  int id8 = (bid & 7) * 64 + (bid >> 3);  // XCD swizzle (512 % 8 == 0)
  int w0 = (id8 & 1) * 32;
  int h = (id8 >> 1) & 63;
  int b = id8 >> 7;
  int t = threadIdx.x;
  int l = t & 63, wv = t >> 6;
  int pxg = wv >> 2, og = wv & 3;
  f4v acc = {0.f, 0.f, 0.f, 0.f};

  for (int id = t; id < 3264; id += 512) {
    int tr = id >> 5, oq8 = id & 31;
    int ky = tr / 34, col = tr % 34;
    int hh = h + ky - 1, ww = w0 + col - 1;
    s8v val = {0, 0, 0, 0, 0, 0, 0, 0};
    if ((unsigned)hh < 64u && (unsigned)ww < 64u)
      val = *(const s8v*)&xb[(((size_t)(b * 64 + hh)) * 64 + ww) * 256 + oq8 * 8];
    int byte = (tr * 512 + oq8 * 16) ^ ((tr & 7) << 4);
    *(s8v*)(Xs + byte) = val;
  }
  __syncthreads();
  int khi = l >> 4, lo = l & 15;
#pragma unroll
  for (int tap = 0; tap < 9; ++tap) {
    int ky = tap / 3, kx = tap % 3;
    int tr = ky * 34 + pxg * 16 + lo + kx;
#pragma unroll
    for (int ks8 = 0; ks8 < 8; ++ks8) {
      int rbyte = (tr * 512 + ks8 * 64 + khi * 16) ^ ((tr & 7) << 4);
      s8v a = *(const s8v*)(Xs + rbyte);
      int kstep = ((ks8 >> 1) * 9 + tap) * 2 + (ks8 & 1);
      s8v bfr = *(const s8v*)&wt[((size_t)(kstep * 4 + og) * 64 + l) * 8];
      acc = __builtin_amdgcn_mfma_f32_16x16x32_bf16(a, bfr, acc, 0, 0, 0);
    }
  }
  int o = og * 16 + lo;
  int pixb = (b * 64 + h) * 64 + w0;
  if (o < 54) {
    float bi = bias[o];
#pragma unroll
    for (int j = 0; j < 4; ++j) {
      int px = pixb + pxg * 16 + khi * 4 + j;
      float vv = acc[j] + bi;
      if (o >= 36) vv = 1.f / (1.f + __expf(-vv));
      off[(size_t)px * 54 + o] = vv;
    }
  }
}

// ---------------- deform sample + dconv: 512 thr, dbuf LDS, 1 barrier/chunk, issue-early ----------------
#define DC_ISSUE(c, V, Q)                                   \
  do {                                                      \
    const unsigned* ip_ = sidx[(c)][px];                    \
    const float* qp_ = swt[(c)][px];                        \
    Q##0 = qp_[0]; Q##1 = qp_[1]; Q##2 = qp_[2]; Q##3 = qp_[3]; \
    V##0 = *(const s8v*)&xb[ip_[0] + chof];                 \
    V##1 = *(const s8v*)&xb[ip_[1] + chof];                 \
    V##2 = *(const s8v*)&xb[ip_[2] + chof];                 \
    V##3 = *(const s8v*)&xb[ip_[3] + chof];                 \
  } while (0)

#define DC_COMMIT(c, V, Q)                                  \
  do {                                                      \
    s8v r_;                                                 \
    _Pragma("unroll") for (int j_ = 0; j_ < 8; ++j_) {      \
      float f_ = Q##0 * bf2f((unsigned short)V##0[j_]) +    \
                 Q##1 * bf2f((unsigned short)V##1[j_]) +    \
                 Q##2 * bf2f((unsigned short)V##2[j_]) +    \
                 Q##3 * bf2f((unsigned short)V##3[j_]);     \
      r_[j_] = (short)f2bf(f_);                             \
    }                                                       \
    *(s8v*)(&At[(c) & 1][0] + wbyte) = r_;                  \
  } while (0)

__global__ __launch_bounds__(512, 4) void k_dconv(const unsigned short* __restrict__ xb,
                                                  const float* __restrict__ off,
                                                  const unsigned short* __restrict__ wt,
                                                  float* __restrict__ y1p,
                                                  float* __restrict__ st1, float* __restrict__ st2) {
  __shared__ unsigned int sidx[18][32][4];
  __shared__ float swt[18][32][4];
  __shared__ char At[2][8192];  // [32 px][128 ch] bf16, XOR-swizzled, double-buffered
  int t = threadIdx.x;
  int l = t & 63, wv = t >> 6;
  int pxg = wv >> 2, og = wv & 3;
  int bid = blockIdx.x;
  int id8 = (bid & 7) * 64 + (bid >> 3);  // XCD swizzle
  int pixb = id8 * 32;
  int b = pixb >> 12, h = (pixb >> 6) & 63, w0 = pixb & 63;

  for (int id = t; id < 576; id += 512) {
    int chunk = id >> 5, ppx = id & 31;
    int g = chunk / 9, kk = chunk % 9;
    const float* op = off + (size_t)(pixb + ppx) * 54;
    float dy = op[(g * 9 + kk) * 2];
    float dx = op[(g * 9 + kk) * 2 + 1];
    float msk = op[36 + g * 9 + kk];
    float py = dy + (float)(h + kk / 3 - 1);
    float pxf = dx + (float)(w0 + ppx + kk % 3 - 1);
    float y0f = floorf(py), x0f = floorf(pxf);
    float ly = py - y0f, lx = pxf - x0f;
    int y0 = (int)y0f, x0 = (int)x0f;
    int y1 = y0 + 1, x1 = x0 + 1;
    float oky0 = (y0 >= 0 && y0 < 64) ? 1.f : 0.f;
    float oky1 = (y1 >= 0 && y1 < 64) ? 1.f : 0.f;
    float okx0 = (x0 >= 0 && x0 < 64) ? 1.f : 0.f;
    float okx1 = (x1 >= 0 && x1 < 64) ? 1.f : 0.f;
    int y0c = min(max(y0, 0), 63), y1c = min(max(y1, 0), 63);
    int x0c = min(max(x0, 0), 63), x1c = min(max(x1, 0), 63);
    unsigned base = (unsigned)(b * 4096);
    unsigned gofs = (unsigned)(g * 128);
    sidx[chunk][ppx][0] = (base + y0c * 64 + x0c) * 256u + gofs;
    sidx[chunk][ppx][1] = (base + y0c * 64 + x1c) * 256u + gofs;
    sidx[chunk][ppx][2] = (base + y1c * 64 + x0c) * 256u + gofs;
    sidx[chunk][ppx][3] = (base + y1c * 64 + x1c) * 256u + gofs;
    swt[chunk][ppx][0] = (1.f - ly) * (1.f - lx) * oky0 * okx0 * msk;
    swt[chunk][ppx][1] = (1.f - ly) * lx * oky0 * okx1 * msk;
    swt[chunk][ppx][2] = ly * (1.f - lx) * oky1 * okx0 * msk;
    swt[chunk][ppx][3] = ly * lx * oky1 * okx1 * msk;
  }
  __syncthreads();

  int px = t >> 4, oq = t & 15;
  unsigned chof = oq * 8u;
  int wbyte = (px * 256 + oq * 16) ^ ((px & 7) << 4);
  int khi = l >> 4, lo = l & 15;
  int trA = pxg * 16 + lo;

  s8v va0, va1, va2, va3, vb0, vb1, vb2, vb3;
  float qa0, qa1, qa2, qa3, qb0, qb1, qb2, qb3;

  DC_ISSUE(0, va, qa);
  DC_COMMIT(0, va, qa);
  DC_ISSUE(1, vb, qb);
  __syncthreads();

  f4v zero = {0.f, 0.f, 0.f, 0.f};
  f4v acc[2] = {zero, zero};

  for (int c = 0; c < 18; ++c) {
#pragma unroll
    for (int ks4 = 0; ks4 < 4; ++ks4) {
      int rbyte = (trA * 256 + ks4 * 64 + khi * 16) ^ ((trA & 7) << 4);
      s8v a = *(const s8v*)(&At[c & 1][0] + rbyte);
      int kstep = c * 4 + ks4;
#pragma unroll
      for (int nf = 0; nf < 2; ++nf) {
        s8v bfr = *(const s8v*)&wt[((size_t)(kstep * 8 + og * 2 + nf) * 64 + l) * 8];
        acc[nf] = __builtin_amdgcn_mfma_f32_16x16x32_bf16(a, bfr, acc[nf], 0, 0, 0);
      }
    }
    if (c < 17) {
      if ((c & 1) == 0) {
        if (c < 16) DC_ISSUE(c + 2, va, qa);
        DC_COMMIT(c + 1, vb, qb);
      } else {
        if (c < 16) DC_ISSUE(c + 2, vb, qb);
        DC_COMMIT(c + 1, va, qa);
      }
    }
    __syncthreads();
  }

  // epilogue: y1p write + fused stats
  float s1v[2], s2v[2];
#pragma unroll
  for (int nf = 0; nf < 2; ++nf) {
    int o = og * 32 + nf * 16 + lo;
    s1v[nf] = 0.f; s2v[nf] = 0.f;
#pragma unroll
    for (int j = 0; j < 4; ++j) {
      float vv = acc[nf][j];
      y1p[(size_t)(pixb + pxg * 16 + khi * 4 + j) * 128 + o] = vv;
      s1v[nf] += vv; s2v[nf] += vv * vv;
    }
  }
  float* red = &swt[0][0][0];
  int r = pxg * 4 + khi;
#pragma unroll
  for (int nf = 0; nf < 2; ++nf) {
    int o = og * 32 + nf * 16 + lo;
    red[r * 128 + o] = s1v[nf];
    red[1024 + r * 128 + o] = s2v[nf];
  }
  __syncthreads();
  if (t < 128) {
    float a1 = 0.f, a2 = 0.f;
#pragma unroll
    for (int rr = 0; rr < 8; ++rr) { a1 += red[rr * 128 + t]; a2 += red[1024 + rr * 128 + t]; }
    atomicAdd(&st1[t], a1);
    atomicAdd(&st2[t], a2);
  }
}

// ---------------- bn1 + relu: f32 NHWC -> bf16 NHWC ----------------
__global__ __launch_bounds__(256) void k_bnrelu1(const float* __restrict__ yp, const float* __restrict__ s1,
                                                 const float* __restrict__ s2, const float* __restrict__ g,
                                                 const float* __restrict__ bb, unsigned short* __restrict__ yb) {
  __shared__ float sc[128], sh[128];
  int t = threadIdx.x;
  if (t < 128) {
    float m = s1[t] * (1.f / 16384.f);
    float var = s2[t] * (1.f / 16384.f) - m * m;
    float s = g[t] * rsqrtf(var + EPSBN);
    sc[t] = s;
    sh[t] = bb[t] - m * s;
  }
  __syncthreads();
  size_t i = ((size_t)blockIdx.x * 256 + t) * 8;
  int c0 = (int)(i & 127);
  float4 u = *(const float4*)&yp[i];
  float4 v = *(const float4*)&yp[i + 4];
  s8v r;
  r[0] = (short)f2bf(fmaxf(0.f, u.x * sc[c0 + 0] + sh[c0 + 0]));
  r[1] = (short)f2bf(fmaxf(0.f, u.y * sc[c0 + 1] + sh[c0 + 1]));
  r[2] = (short)f2bf(fmaxf(0.f, u.z * sc[c0 + 2] + sh[c0 + 2]));
  r[3] = (short)f2bf(fmaxf(0.f, u.w * sc[c0 + 3] + sh[c0 + 3]));
  r[4] = (short)f2bf(fmaxf(0.f, v.x * sc[c0 + 4] + sh[c0 + 4]));
  r[5] = (short)f2bf(fmaxf(0.f, v.y * sc[c0 + 5] + sh[c0 + 5]));
  r[6] = (short)f2bf(fmaxf(0.f, v.z * sc[c0 + 6] + sh[c0 + 6]));
  r[7] = (short)f2bf(fmaxf(0.f, v.w * sc[c0 + 7] + sh[c0 + 7]));
  *(s8v*)&yb[i] = r;
}

// ---------------- conv2: 512 thr, single-stage LDS (bf16 input), fused stats ----------------
__global__ __launch_bounds__(512, 4) void k_conv2(const unsigned short* __restrict__ yb,
                                                  const unsigned short* __restrict__ wt,
                                                  float* __restrict__ y2p,
                                                  float* __restrict__ st1, float* __restrict__ st2) {
  __shared__ char Bs[102 * 256];  // [3*34 rows][128 ch] bf16, XOR-swizzled
  int bid = blockIdx.x;
  int id8 = (bid & 7) * 64 + (bid >> 3);  // XCD swizzle
  int w0 = (id8 & 1) * 32;
  int h = (id8 >> 1) & 63;
  int b = id8 >> 7;
  int t = threadIdx.x;
  int l = t & 63, wv = t >> 6;
  int pxg = wv >> 2, og = wv & 3;
  f4v zero = {0.f, 0.f, 0.f, 0.f};
  f4v acc[2] = {zero, zero};

  for (int id = t; id < 1632; id += 512) {
    int tr = id >> 4, oq = id & 15;
    int ky = tr / 34, col = tr % 34;
    int hh = h + ky - 1, ww = w0 + col - 1;
    s8v val = {0, 0, 0, 0, 0, 0, 0, 0};
    if ((unsigned)hh < 64u && (unsigned)ww < 64u)
      val = *(const s8v*)&yb[(((size_t)(b * 64 + hh)) * 64 + ww) * 128 + oq * 8];
    int byte = (tr * 256 + oq * 16) ^ ((tr & 7) << 4);
    *(s8v*)(Bs + byte) = val;
  }
  __syncthreads();
  int khi = l >> 4, lo = l & 15;
#pragma unroll
  for (int tap = 0; tap < 9; ++tap) {
    int ky = tap / 3, kx = tap % 3;
    int tr = ky * 34 + pxg * 16 + lo + kx;
#pragma unroll
    for (int ks4 = 0; ks4 < 4; ++ks4) {
      int rbyte = (tr * 256 + ks4 * 64 + khi * 16) ^ ((tr & 7) << 4);
      s8v a = *(const s8v*)(Bs + rbyte);
      int kstep = ((ks4 >> 1) * 9 + tap) * 2 + (ks4 & 1);
#pragma unroll
      for (int nf = 0; nf < 2; ++nf) {
        s8v bfr = *(const s8v*)&wt[((size_t)(kstep * 8 + og * 2 + nf) * 64 + l) * 8];
        acc[nf] = __builtin_amdgcn_mfma_f32_16x16x32_bf16(a, bfr, acc[nf], 0, 0, 0);
      }
    }
  }
  int pixb = (b * 64 + h) * 64 + w0;
  float s1v[2], s2v[2];
#pragma unroll
  for (int nf = 0; nf < 2; ++nf) {
    int o = og * 32 + nf * 16 + lo;
    s1v[nf] = 0.f; s2v[nf] = 0.f;
#pragma unroll
    for (int j = 0; j < 4; ++j) {
      float vv = acc[nf][j];
      y2p[(size_t)(pixb + pxg * 16 + khi * 4 + j) * 128 + o] = vv;
      s1v[nf] += vv; s2v[nf] += vv * vv;
    }
  }
  __syncthreads();
  float* red = (float*)Bs;
  int r = pxg * 4 + khi;
#pragma unroll
  for (int nf = 0; nf < 2; ++nf) {
    int o = og * 32 + nf * 16 + lo;
    red[r * 128 + o] = s1v[nf];
    red[1024 + r * 128 + o] = s2v[nf];
  }
  __syncthreads();
  if (t < 128) {
    float a1 = 0.f, a2 = 0.f;
#pragma unroll
    for (int rr = 0; rr < 8; ++rr) { a1 += red[rr * 128 + t]; a2 += red[1024 + rr * 128 + t]; }
    atomicAdd(&st1[t], a1);
    atomicAdd(&st2[t], a2);
  }
}

// ---------------- bn2 + relu + NHWC -> NCHW ----------------
__global__ __launch_bounds__(256) void k_bnrelu2(const float* __restrict__ yp, const float* __restrict__ s1,
                                                 const float* __restrict__ s2, const float* __restrict__ g,
                                                 const float* __restrict__ bb, float* __restrict__ out) {
  __shared__ float sc[128], sh[128];
  int t = threadIdx.x;
  if (t < 128) {
    float m = s1[t] * (1.f / 16384.f);
    float var = s2[t] * (1.f / 16384.f) - m * m;
    float s = g[t] * rsqrtf(var + EPSBN);
    sc[t] = s;
    sh[t] = bb[t] - m * s;
  }
  __syncthreads();
  int bh = blockIdx.x;
  int b = bh >> 6, h = bh & 63;
  const float* src = yp + (size_t)bh * 64 * 128;
  for (int id = t; id < 64 * 128; id += 256) {
    int w = id & 63, o = id >> 6;
    float v = src[w * 128 + o];
    v = fmaxf(0.f, v * sc[o] + sh[o]);
    out[(((size_t)b * 128 + o) * 64 + h) * 64 + w] = v;
  }
}

extern "C" void kernel_launch(void* const* d_in, const int* in_sizes, int n_in,
                              void* d_out, int out_size, void* d_ws, size_t ws_size,
                              hipStream_t stream) {
  const float* in_v = (const float*)d_in[0];
  const float* in_i = (const float*)d_in[1];
  const float* off_w = (const float*)d_in[2];
  const float* off_b = (const float*)d_in[3];
  const float* dconv_w = (const float*)d_in[4];
  const float* bn1_g = (const float*)d_in[5];
  const float* bn1_b = (const float*)d_in[6];
  const float* conv2_w = (const float*)d_in[7];
  const float* bn2_g = (const float*)d_in[8];
  const float* bn2_b = (const float*)d_in[9];
  float* out = (float*)d_out;

  char* w = (char*)d_ws;
  unsigned short* xb = (unsigned short*)w;      w += (size_t)16384 * 256 * 2;  // 8 MB
  float* off_nhwc = (float*)w;                  w += (size_t)16384 * 54 * 4;   // 3.4 MB
  unsigned short* wtf_off = (unsigned short*)w; w += (size_t)18432 * 8 * 2;    // 288 KB
  unsigned short* wtf_d = (unsigned short*)w;   w += (size_t)36864 * 8 * 2;    // 576 KB
  unsigned short* wtf_2 = (unsigned short*)w;   w += (size_t)18432 * 8 * 2;    // 288 KB
  float* y1p = (float*)w;                       w += (size_t)16384 * 128 * 4;  // 8 MB
  unsigned short* y1b = (unsigned short*)w;     w += (size_t)16384 * 128 * 2;  // 4 MB
  float* y2p = (float*)w;                       w += (size_t)16384 * 128 * 4;  // 8 MB
  float* stats = (float*)w;                     w += 512 * 4;

  hipMemsetAsync(stats, 0, 512 * 4, stream);
  k_pack<<<dim3(128, 4, 4), dim3(32, 8), 0, stream>>>(in_v, in_i, xb);
  k_wprep_off<<<72, 256, 0, stream>>>(off_w, wtf_off);
  k_wprep_d<<<144, 256, 0, stream>>>(dconv_w, wtf_d);
  k_wprep_2<<<72, 256, 0, stream>>>(conv2_w, wtf_2);
  k_offconv<<<512, 512, 0, stream>>>(xb, wtf_off, off_b, off_nhwc);
  k_dconv<<<512, 512, 0, stream>>>(xb, off_nhwc, wtf_d, y1p, stats, stats + 128);
  k_bnrelu1<<<1024, 256, 0, stream>>>(y1p, stats, stats + 128, bn1_g, bn1_b, y1b);
  k_conv2<<<512, 512, 0, stream>>>(y1b, wtf_2, y2p, stats + 256, stats + 384);
  k_bnrelu2<<<256, 256, 0, stream>>>(y2p, stats + 256, stats + 384, bn2_g, bn2_b, out);
}

// Round 4
// 178.064 us; speedup vs baseline: 3.2839x; 1.0102x over previous
//
#include <hip/hip_runtime.h>

#define EPSBN 1e-5f

using s8v = __attribute__((ext_vector_type(8))) short;
using f4v = __attribute__((ext_vector_type(4))) float;

__device__ inline unsigned short f2bf(float f) {
  unsigned u = __float_as_uint(f);
  return (unsigned short)((u + 0x7FFFu + ((u >> 16) & 1u)) >> 16);
}
__device__ inline float bf2f(unsigned short h) {
  return __uint_as_float(((unsigned)h) << 16);
}

// ---------------- pack: concat(v,i) + NCHW f32 -> NHWC bf16 ----------------
__global__ __launch_bounds__(256) void k_pack(const float* __restrict__ v, const float* __restrict__ im,
                                              unsigned short* __restrict__ xb) {
  __shared__ float tile[64][33];
  int b = blockIdx.z;
  int hw0 = blockIdx.x * 32;
  int c0 = blockIdx.y * 64;
  int tx = threadIdx.x, ty = threadIdx.y;
#pragma unroll
  for (int i = 0; i < 64; i += 8) {
    int c = c0 + ty + i;
    const float* src = (c < 128) ? (v + ((size_t)b * 128 + c) * 4096)
                                 : (im + ((size_t)b * 128 + (c - 128)) * 4096);
    tile[ty + i][tx] = src[hw0 + tx];
  }
  __syncthreads();
#pragma unroll
  for (int i = 0; i < 32; i += 8) {
    int hw = hw0 + ty + i;
    ushort2 o;
    o.x = f2bf(tile[2 * tx][ty + i]);
    o.y = f2bf(tile[2 * tx + 1][ty + i]);
    *(ushort2*)&xb[((size_t)(b * 4096 + hw)) * 256 + c0 + 2 * tx] = o;
  }
}

// ---------------- weight prep: fragment-major bf16 (verified mappings, unchanged) ----------------
__global__ __launch_bounds__(256) void k_wprep_off(const float* __restrict__ w, unsigned short* __restrict__ wt) {
  int id = blockIdx.x * 256 + threadIdx.x;  // 72*4*64 = 18432
  int lane = id & 63;
  int nb = (id >> 6) & 3;
  int ks = id >> 8;
  int ks2 = ks & 1, tap = (ks >> 1) % 9, cc = ks / 18;
  int o = nb * 16 + (lane & 15);
  int cb = cc * 64 + ks2 * 32 + ((lane >> 4) * 8);
  s8v r;
#pragma unroll
  for (int j = 0; j < 8; ++j) {
    float val = (o < 54) ? w[((size_t)o * 256 + cb + j) * 9 + tap] : 0.f;
    r[j] = (short)f2bf(val);
  }
  *(s8v*)&wt[(size_t)id * 8] = r;
}
__global__ __launch_bounds__(256) void k_wprep_d(const float* __restrict__ w, unsigned short* __restrict__ wt) {
  int id = blockIdx.x * 256 + threadIdx.x;  // 72*8*64 = 36864
  int lane = id & 63;
  int nb = (id >> 6) & 7;
  int kstep = id >> 9;
  int chunk = kstep >> 2, ks4 = kstep & 3;
  int g = chunk / 9, kk = chunk % 9;
  int o = nb * 16 + (lane & 15);
  int cb = g * 128 + ks4 * 32 + ((lane >> 4) * 8);
  s8v r;
#pragma unroll
  for (int j = 0; j < 8; ++j) r[j] = (short)f2bf(w[((size_t)o * 256 + cb + j) * 9 + kk]);
  *(s8v*)&wt[(size_t)id * 8] = r;
}
__global__ __launch_bounds__(256) void k_wprep_2(const float* __restrict__ w, unsigned short* __restrict__ wt) {
  int id = blockIdx.x * 256 + threadIdx.x;  // 36*8*64 = 18432
  int lane = id & 63;
  int nb = (id >> 6) & 7;
  int kstep = id >> 9;
  int ks2 = kstep & 1, tap = (kstep >> 1) % 9, cc = kstep / 18;
  int o = nb * 16 + (lane & 15);
  int cb = cc * 64 + ks2 * 32 + ((lane >> 4) * 8);
  s8v r;
#pragma unroll
  for (int j = 0; j < 8; ++j) r[j] = (short)f2bf(w[((size_t)o * 128 + cb + j) * 9 + tap]);
  *(s8v*)&wt[(size_t)id * 8] = r;
}

// ---------------- offset conv: waves = og(4) x kh(2), M=32, N=16/wave ----------------
__global__ __launch_bounds__(512, 3) void k_offconv(const unsigned short* __restrict__ xb,
                                                    const unsigned short* __restrict__ wt,
                                                    const float* __restrict__ bias,
                                                    float* __restrict__ off) {
  __shared__ char Xs[102 * 512];  // [3*34 rows][256 ch] bf16, XOR-swizzled
  __shared__ float redx[2048];    // kh pair-reduction
  int bid = blockIdx.x;
  int id8 = (bid & 7) * 64 + (bid >> 3);  // XCD swizzle (512 % 8 == 0)
  int w0 = (id8 & 1) * 32;
  int h = (id8 >> 1) & 63;
  int b = id8 >> 7;
  int t = threadIdx.x;
  int l = t & 63, wv = t >> 6;
  int og = wv & 3, kh = wv >> 2;
  f4v zero = {0.f, 0.f, 0.f, 0.f};
  f4v acc[2] = {zero, zero};

  for (int id = t; id < 3264; id += 512) {
    int tr = id >> 5, oq8 = id & 31;
    int ky = tr / 34, col = tr % 34;
    int hh = h + ky - 1, ww = w0 + col - 1;
    s8v val = {0, 0, 0, 0, 0, 0, 0, 0};
    if ((unsigned)hh < 64u && (unsigned)ww < 64u)
      val = *(const s8v*)&xb[(((size_t)(b * 64 + hh)) * 64 + ww) * 256 + oq8 * 8];
    int byte = (tr * 512 + oq8 * 16) ^ ((tr & 7) << 4);
    *(s8v*)(Xs + byte) = val;
  }
  __syncthreads();
  int khi = l >> 4, lo = l & 15;
#pragma unroll
  for (int tap = 0; tap < 9; ++tap) {
    int ky = tap / 3, kx = tap % 3;
#pragma unroll
    for (int s = 0; s < 4; ++s) {
      int cc = kh * 2 + (s >> 1);
      int ks2 = s & 1;
      int kstep = cc * 18 + tap * 2 + ks2;
      int chb = cc * 128 + ks2 * 64 + khi * 16;
      s8v bfr = *(const s8v*)&wt[((size_t)(kstep * 4 + og) * 64 + l) * 8];
#pragma unroll
      for (int m = 0; m < 2; ++m) {
        int tr = ky * 34 + m * 16 + lo + kx;
        int rbyte = (tr * 512 + chb) ^ ((tr & 7) << 4);
        s8v a = *(const s8v*)(Xs + rbyte);
        acc[m] = __builtin_amdgcn_mfma_f32_16x16x32_bf16(a, bfr, acc[m], 0, 0, 0);
      }
    }
  }
  // kh-pair reduce
  if (kh == 1) {
#pragma unroll
    for (int m = 0; m < 2; ++m)
#pragma unroll
      for (int j = 0; j < 4; ++j) redx[((og * 64 + l) * 2 + m) * 4 + j] = acc[m][j];
  }
  __syncthreads();
  if (kh == 0) {
    int o = og * 16 + lo;
    int pixb = (b * 64 + h) * 64 + w0;
    if (o < 54) {
      float bi = bias[o];
#pragma unroll
      for (int m = 0; m < 2; ++m)
#pragma unroll
        for (int j = 0; j < 4; ++j) {
          int px = pixb + m * 16 + khi * 4 + j;
          float vv = acc[m][j] + redx[((og * 64 + l) * 2 + m) * 4 + j] + bi;
          if (o >= 36) vv = 1.f / (1.f + __expf(-vv));
          off[(size_t)px * 54 + o] = vv;
        }
    }
  }
}

// ---------------- deform sample + dconv: waves = og(8), M=32, dbuf + issue-early ----------------
#define DC_ISSUE(c, V, Q)                                   \
  do {                                                      \
    const unsigned* ip_ = sidx[(c)][px];                    \
    const float* qp_ = swt[(c)][px];                        \
    Q##0 = qp_[0]; Q##1 = qp_[1]; Q##2 = qp_[2]; Q##3 = qp_[3]; \
    V##0 = *(const s8v*)&xb[ip_[0] + chof];                 \
    V##1 = *(const s8v*)&xb[ip_[1] + chof];                 \
    V##2 = *(const s8v*)&xb[ip_[2] + chof];                 \
    V##3 = *(const s8v*)&xb[ip_[3] + chof];                 \
  } while (0)

#define DC_COMMIT(c, V, Q)                                  \
  do {                                                      \
    unsigned rr_[4];                                        \
    _Pragma("unroll") for (int jp_ = 0; jp_ < 4; ++jp_) {   \
      float f0_ = Q##0 * bf2f((unsigned short)V##0[2 * jp_]) +     \
                  Q##1 * bf2f((unsigned short)V##1[2 * jp_]) +     \
                  Q##2 * bf2f((unsigned short)V##2[2 * jp_]) +     \
                  Q##3 * bf2f((unsigned short)V##3[2 * jp_]);      \
      float f1_ = Q##0 * bf2f((unsigned short)V##0[2 * jp_ + 1]) + \
                  Q##1 * bf2f((unsigned short)V##1[2 * jp_ + 1]) + \
                  Q##2 * bf2f((unsigned short)V##2[2 * jp_ + 1]) + \
                  Q##3 * bf2f((unsigned short)V##3[2 * jp_ + 1]);  \
      unsigned p_;                                          \
      asm("v_cvt_pk_bf16_f32 %0, %1, %2" : "=v"(p_) : "v"(f0_), "v"(f1_)); \
      rr_[jp_] = p_;                                        \
    }                                                       \
    *(int4*)(&At[(c) & 1][0] + wbyte) = *(int4*)rr_;        \
  } while (0)

__global__ __launch_bounds__(512, 3) void k_dconv(const unsigned short* __restrict__ xb,
                                                  const float* __restrict__ off,
                                                  const unsigned short* __restrict__ wt,
                                                  float* __restrict__ y1p,
                                                  float* __restrict__ st1, float* __restrict__ st2) {
  __shared__ unsigned int sidx[18][32][4];
  __shared__ float swt[18][32][4];
  __shared__ char At[2][8192];  // [32 px][128 ch] bf16, XOR-swizzled, double-buffered
  int t = threadIdx.x;
  int l = t & 63, og = t >> 6;  // wave == o-slice
  int bid = blockIdx.x;
  int id8 = (bid & 7) * 64 + (bid >> 3);  // XCD swizzle
  int pixb = id8 * 32;
  int b = pixb >> 12, h = (pixb >> 6) & 63, w0 = pixb & 63;

  for (int id = t; id < 576; id += 512) {
    int chunk = id >> 5, ppx = id & 31;
    int g = chunk / 9, kk = chunk % 9;
    const float* op = off + (size_t)(pixb + ppx) * 54;
    float dy = op[(g * 9 + kk) * 2];
    float dx = op[(g * 9 + kk) * 2 + 1];
    float msk = op[36 + g * 9 + kk];
    float py = dy + (float)(h + kk / 3 - 1);
    float pxf = dx + (float)(w0 + ppx + kk % 3 - 1);
    float y0f = floorf(py), x0f = floorf(pxf);
    float ly = py - y0f, lx = pxf - x0f;
    int y0 = (int)y0f, x0 = (int)x0f;
    int y1 = y0 + 1, x1 = x0 + 1;
    float oky0 = (y0 >= 0 && y0 < 64) ? 1.f : 0.f;
    float oky1 = (y1 >= 0 && y1 < 64) ? 1.f : 0.f;
    float okx0 = (x0 >= 0 && x0 < 64) ? 1.f : 0.f;
    float okx1 = (x1 >= 0 && x1 < 64) ? 1.f : 0.f;
    int y0c = min(max(y0, 0), 63), y1c = min(max(y1, 0), 63);
    int x0c = min(max(x0, 0), 63), x1c = min(max(x1, 0), 63);
    unsigned base = (unsigned)(b * 4096);
    unsigned gofs = (unsigned)(g * 128);
    sidx[chunk][ppx][0] = (base + y0c * 64 + x0c) * 256u + gofs;
    sidx[chunk][ppx][1] = (base + y0c * 64 + x1c) * 256u + gofs;
    sidx[chunk][ppx][2] = (base + y1c * 64 + x0c) * 256u + gofs;
    sidx[chunk][ppx][3] = (base + y1c * 64 + x1c) * 256u + gofs;
    swt[chunk][ppx][0] = (1.f - ly) * (1.f - lx) * oky0 * okx0 * msk;
    swt[chunk][ppx][1] = (1.f - ly) * lx * oky0 * okx1 * msk;
    swt[chunk][ppx][2] = ly * (1.f - lx) * oky1 * okx0 * msk;
    swt[chunk][ppx][3] = ly * lx * oky1 * okx1 * msk;
  }
  __syncthreads();

  int px = t >> 4, oq = t & 15;
  unsigned chof = oq * 8u;
  int wbyte = (px * 256 + oq * 16) ^ ((px & 7) << 4);
  int khi = l >> 4, lo = l & 15;

  s8v va0, va1, va2, va3, vb0, vb1, vb2, vb3;
  float qa0, qa1, qa2, qa3, qb0, qb1, qb2, qb3;

  DC_ISSUE(0, va, qa);
  DC_COMMIT(0, va, qa);
  DC_ISSUE(1, vb, qb);
  __syncthreads();

  f4v zero = {0.f, 0.f, 0.f, 0.f};
  f4v acc[2] = {zero, zero};

  for (int c = 0; c < 18; ++c) {
#pragma unroll
    for (int ks4 = 0; ks4 < 4; ++ks4) {
      int kstep = c * 4 + ks4;
      s8v bfr = *(const s8v*)&wt[((size_t)(kstep * 8 + og) * 64 + l) * 8];
      int chb = ks4 * 64 + khi * 16;
#pragma unroll
      for (int m = 0; m < 2; ++m) {
        int trA = m * 16 + lo;
        int rbyte = (trA * 256 + chb) ^ ((trA & 7) << 4);
        s8v a = *(const s8v*)(&At[c & 1][0] + rbyte);
        acc[m] = __builtin_amdgcn_mfma_f32_16x16x32_bf16(a, bfr, acc[m], 0, 0, 0);
      }
    }
    if (c < 17) {
      if ((c & 1) == 0) {
        if (c < 16) DC_ISSUE(c + 2, va, qa);
        DC_COMMIT(c + 1, vb, qb);
      } else {
        if (c < 16) DC_ISSUE(c + 2, vb, qb);
        DC_COMMIT(c + 1, va, qa);
      }
    }
    __syncthreads();
  }

  // epilogue: y1p write + fused stats
  int o = og * 16 + lo;
  float s1v = 0.f, s2v = 0.f;
#pragma unroll
  for (int m = 0; m < 2; ++m)
#pragma unroll
    for (int j = 0; j < 4; ++j) {
      float vv = acc[m][j];
      y1p[(size_t)(pixb + m * 16 + khi * 4 + j) * 128 + o] = vv;
      s1v += vv; s2v += vv * vv;
    }
  float* red = &swt[0][0][0];
  red[khi * 128 + o] = s1v;
  red[512 + khi * 128 + o] = s2v;
  __syncthreads();
  if (t < 128) {
    float a1 = 0.f, a2 = 0.f;
#pragma unroll
    for (int rr = 0; rr < 4; ++rr) { a1 += red[rr * 128 + t]; a2 += red[512 + rr * 128 + t]; }
    atomicAdd(&st1[t], a1);
    atomicAdd(&st2[t], a2);
  }
}

// ---------------- bn1 + relu: f32 NHWC -> bf16 NHWC ----------------
__global__ __launch_bounds__(256) void k_bnrelu1(const float* __restrict__ yp, const float* __restrict__ s1,
                                                 const float* __restrict__ s2, const float* __restrict__ g,
                                                 const float* __restrict__ bb, unsigned short* __restrict__ yb) {
  __shared__ float sc[128], sh[128];
  int t = threadIdx.x;
  if (t < 128) {
    float m = s1[t] * (1.f / 16384.f);
    float var = s2[t] * (1.f / 16384.f) - m * m;
    float s = g[t] * rsqrtf(var + EPSBN);
    sc[t] = s;
    sh[t] = bb[t] - m * s;
  }
  __syncthreads();
  size_t i = ((size_t)blockIdx.x * 256 + t) * 8;
  int c0 = (int)(i & 127);
  float4 u = *(const float4*)&yp[i];
  float4 v = *(const float4*)&yp[i + 4];
  s8v r;
  r[0] = (short)f2bf(fmaxf(0.f, u.x * sc[c0 + 0] + sh[c0 + 0]));
  r[1] = (short)f2bf(fmaxf(0.f, u.y * sc[c0 + 1] + sh[c0 + 1]));
  r[2] = (short)f2bf(fmaxf(0.f, u.z * sc[c0 + 2] + sh[c0 + 2]));
  r[3] = (short)f2bf(fmaxf(0.f, u.w * sc[c0 + 3] + sh[c0 + 3]));
  r[4] = (short)f2bf(fmaxf(0.f, v.x * sc[c0 + 4] + sh[c0 + 4]));
  r[5] = (short)f2bf(fmaxf(0.f, v.y * sc[c0 + 5] + sh[c0 + 5]));
  r[6] = (short)f2bf(fmaxf(0.f, v.z * sc[c0 + 6] + sh[c0 + 6]));
  r[7] = (short)f2bf(fmaxf(0.f, v.w * sc[c0 + 7] + sh[c0 + 7]));
  *(s8v*)&yb[i] = r;
}

// ---------------- conv2: waves = og(8), M=32, fused stats ----------------
__global__ __launch_bounds__(512, 3) void k_conv2(const unsigned short* __restrict__ yb,
                                                  const unsigned short* __restrict__ wt,
                                                  float* __restrict__ y2p,
                                                  float* __restrict__ st1, float* __restrict__ st2) {
  __shared__ char Bs[102 * 256];  // [3*34 rows][128 ch] bf16, XOR-swizzled
  int bid = blockIdx.x;
  int id8 = (bid & 7) * 64 + (bid >> 3);  // XCD swizzle
  int w0 = (id8 & 1) * 32;
  int h = (id8 >> 1) & 63;
  int b = id8 >> 7;
  int t = threadIdx.x;
  int l = t & 63, og = t >> 6;
  f4v zero = {0.f, 0.f, 0.f, 0.f};
  f4v acc[2] = {zero, zero};

  for (int id = t; id < 1632; id += 512) {
    int tr = id >> 4, oq = id & 15;
    int ky = tr / 34, col = tr % 34;
    int hh = h + ky - 1, ww = w0 + col - 1;
    s8v val = {0, 0, 0, 0, 0, 0, 0, 0};
    if ((unsigned)hh < 64u && (unsigned)ww < 64u)
      val = *(const s8v*)&yb[(((size_t)(b * 64 + hh)) * 64 + ww) * 128 + oq * 8];
    int byte = (tr * 256 + oq * 16) ^ ((tr & 7) << 4);
    *(s8v*)(Bs + byte) = val;
  }
  __syncthreads();
  int khi = l >> 4, lo = l & 15;
#pragma unroll
  for (int tap = 0; tap < 9; ++tap) {
    int ky = tap / 3, kx = tap % 3;
#pragma unroll
    for (int ks4 = 0; ks4 < 4; ++ks4) {
      int kstep = ((ks4 >> 1) * 9 + tap) * 2 + (ks4 & 1);
      s8v bfr = *(const s8v*)&wt[((size_t)(kstep * 8 + og) * 64 + l) * 8];
      int chb = ks4 * 64 + khi * 16;
#pragma unroll
      for (int m = 0; m < 2; ++m) {
        int tr = ky * 34 + m * 16 + lo + kx;
        int rbyte = (tr * 256 + chb) ^ ((tr & 7) << 4);
        s8v a = *(const s8v*)(Bs + rbyte);
        acc[m] = __builtin_amdgcn_mfma_f32_16x16x32_bf16(a, bfr, acc[m], 0, 0, 0);
      }
    }
  }
  __syncthreads();  // Bs reads done before red reuse
  int pixb = (b * 64 + h) * 64 + w0;
  int o = og * 16 + lo;
  float s1v = 0.f, s2v = 0.f;
#pragma unroll
  for (int m = 0; m < 2; ++m)
#pragma unroll
    for (int j = 0; j < 4; ++j) {
      float vv = acc[m][j];
      y2p[(size_t)(pixb + m * 16 + khi * 4 + j) * 128 + o] = vv;
      s1v += vv; s2v += vv * vv;
    }
  float* red = (float*)Bs;
  red[khi * 128 + o] = s1v;
  red[512 + khi * 128 + o] = s2v;
  __syncthreads();
  if (t < 128) {
    float a1 = 0.f, a2 = 0.f;
#pragma unroll
    for (int rr = 0; rr < 4; ++rr) { a1 += red[rr * 128 + t]; a2 += red[512 + rr * 128 + t]; }
    atomicAdd(&st1[t], a1);
    atomicAdd(&st2[t], a2);
  }
}

// ---------------- bn2 + relu + NHWC -> NCHW ----------------
__global__ __launch_bounds__(256) void k_bnrelu2(const float* __restrict__ yp, const float* __restrict__ s1,
                                                 const float* __restrict__ s2, const float* __restrict__ g,
                                                 const float* __restrict__ bb, float* __restrict__ out) {
  __shared__ float sc[128], sh[128];
  int t = threadIdx.x;
  if (t < 128) {
    float m = s1[t] * (1.f / 16384.f);
    float var = s2[t] * (1.f / 16384.f) - m * m;
    float s = g[t] * rsqrtf(var + EPSBN);
    sc[t] = s;
    sh[t] = bb[t] - m * s;
  }
  __syncthreads();
  int bh = blockIdx.x;
  int b = bh >> 6, h = bh & 63;
  const float* src = yp + (size_t)bh * 64 * 128;
  for (int id = t; id < 64 * 128; id += 256) {
    int w = id & 63, o = id >> 6;
    float v = src[w * 128 + o];
    v = fmaxf(0.f, v * sc[o] + sh[o]);
    out[(((size_t)b * 128 + o) * 64 + h) * 64 + w] = v;
  }
}

extern "C" void kernel_launch(void* const* d_in, const int* in_sizes, int n_in,
                              void* d_out, int out_size, void* d_ws, size_t ws_size,
                              hipStream_t stream) {
  const float* in_v = (const float*)d_in[0];
  const float* in_i = (const float*)d_in[1];
  const float* off_w = (const float*)d_in[2];
  const float* off_b = (const float*)d_in[3];
  const float* dconv_w = (const float*)d_in[4];
  const float* bn1_g = (const float*)d_in[5];
  const float* bn1_b = (const float*)d_in[6];
  const float* conv2_w = (const float*)d_in[7];
  const float* bn2_g = (const float*)d_in[8];
  const float* bn2_b = (const float*)d_in[9];
  float* out = (float*)d_out;

  char* w = (char*)d_ws;
  unsigned short* xb = (unsigned short*)w;      w += (size_t)16384 * 256 * 2;  // 8 MB
  float* off_nhwc = (float*)w;                  w += (size_t)16384 * 54 * 4;   // 3.4 MB
  unsigned short* wtf_off = (unsigned short*)w; w += (size_t)18432 * 8 * 2;    // 288 KB
  unsigned short* wtf_d = (unsigned short*)w;   w += (size_t)36864 * 8 * 2;    // 576 KB
  unsigned short* wtf_2 = (unsigned short*)w;   w += (size_t)18432 * 8 * 2;    // 288 KB
  float* y1p = (float*)w;                       w += (size_t)16384 * 128 * 4;  // 8 MB
  unsigned short* y1b = (unsigned short*)w;     w += (size_t)16384 * 128 * 2;  // 4 MB
  float* y2p = (float*)w;                       w += (size_t)16384 * 128 * 4;  // 8 MB
  float* stats = (float*)w;                     w += 512 * 4;

  hipMemsetAsync(stats, 0, 512 * 4, stream);
  k_pack<<<dim3(128, 4, 4), dim3(32, 8), 0, stream>>>(in_v, in_i, xb);
  k_wprep_off<<<72, 256, 0, stream>>>(off_w, wtf_off);
  k_wprep_d<<<144, 256, 0, stream>>>(dconv_w, wtf_d);
  k_wprep_2<<<72, 256, 0, stream>>>(conv2_w, wtf_2);
  k_offconv<<<512, 512, 0, stream>>>(xb, wtf_off, off_b, off_nhwc);
  k_dconv<<<512, 512, 0, stream>>>(xb, off_nhwc, wtf_d, y1p, stats, stats + 128);
  k_bnrelu1<<<1024, 256, 0, stream>>>(y1p, stats, stats + 128, bn1_g, bn1_b, y1b);
  k_conv2<<<512, 512, 0, stream>>>(y1b, wtf_2, y2p, stats + 256, stats + 384);
  k_bnrelu2<<<256, 256, 0, stream>>>(y2p, stats + 256, stats + 384, bn2_g, bn2_b, out);
}

// Round 6
// 170.954 us; speedup vs baseline: 3.4204x; 1.0416x over previous
//
#include <hip/hip_runtime.h>

#define EPSBN 1e-5f

using s8v = __attribute__((ext_vector_type(8))) short;
using f4v = __attribute__((ext_vector_type(4))) float;

__device__ inline unsigned short f2bf(float f) {
  unsigned u = __float_as_uint(f);
  return (unsigned short)((u + 0x7FFFu + ((u >> 16) & 1u)) >> 16);
}
__device__ inline float bf2f(unsigned short h) {
  return __uint_as_float(((unsigned)h) << 16);
}

// ---------------- pack: concat(v,i) + NCHW f32 -> NHWC bf16 ----------------
__global__ __launch_bounds__(256) void k_pack(const float* __restrict__ v, const float* __restrict__ im,
                                              unsigned short* __restrict__ xb) {
  __shared__ float tile[64][33];
  int b = blockIdx.z;
  int hw0 = blockIdx.x * 32;
  int c0 = blockIdx.y * 64;
  int tx = threadIdx.x, ty = threadIdx.y;
#pragma unroll
  for (int i = 0; i < 64; i += 8) {
    int c = c0 + ty + i;
    const float* src = (c < 128) ? (v + ((size_t)b * 128 + c) * 4096)
                                 : (im + ((size_t)b * 128 + (c - 128)) * 4096);
    tile[ty + i][tx] = src[hw0 + tx];
  }
  __syncthreads();
#pragma unroll
  for (int i = 0; i < 32; i += 8) {
    int hw = hw0 + ty + i;
    ushort2 o;
    o.x = f2bf(tile[2 * tx][ty + i]);
    o.y = f2bf(tile[2 * tx + 1][ty + i]);
    *(ushort2*)&xb[((size_t)(b * 4096 + hw)) * 256 + c0 + 2 * tx] = o;
  }
}

// ---------------- weight prep: fragment-major bf16 (verified mappings, unchanged) ----------------
__global__ __launch_bounds__(256) void k_wprep_off(const float* __restrict__ w, unsigned short* __restrict__ wt) {
  int id = blockIdx.x * 256 + threadIdx.x;  // 72*4*64 = 18432
  int lane = id & 63;
  int nb = (id >> 6) & 3;
  int ks = id >> 8;
  int ks2 = ks & 1, tap = (ks >> 1) % 9, cc = ks / 18;
  int o = nb * 16 + (lane & 15);
  int cb = cc * 64 + ks2 * 32 + ((lane >> 4) * 8);
  s8v r;
#pragma unroll
  for (int j = 0; j < 8; ++j) {
    float val = (o < 54) ? w[((size_t)o * 256 + cb + j) * 9 + tap] : 0.f;
    r[j] = (short)f2bf(val);
  }
  *(s8v*)&wt[(size_t)id * 8] = r;
}
__global__ __launch_bounds__(256) void k_wprep_d(const float* __restrict__ w, unsigned short* __restrict__ wt) {
  int id = blockIdx.x * 256 + threadIdx.x;  // 72*8*64 = 36864
  int lane = id & 63;
  int nb = (id >> 6) & 7;
  int kstep = id >> 9;
  int chunk = kstep >> 2, ks4 = kstep & 3;
  int g = chunk / 9, kk = chunk % 9;
  int o = nb * 16 + (lane & 15);
  int cb = g * 128 + ks4 * 32 + ((lane >> 4) * 8);
  s8v r;
#pragma unroll
  for (int j = 0; j < 8; ++j) r[j] = (short)f2bf(w[((size_t)o * 256 + cb + j) * 9 + kk]);
  *(s8v*)&wt[(size_t)id * 8] = r;
}
__global__ __launch_bounds__(256) void k_wprep_2(const float* __restrict__ w, unsigned short* __restrict__ wt) {
  int id = blockIdx.x * 256 + threadIdx.x;  // 36*8*64 = 18432
  int lane = id & 63;
  int nb = (id >> 6) & 7;
  int kstep = id >> 9;
  int ks2 = kstep & 1, tap = (kstep >> 1) % 9, cc = kstep / 18;
  int o = nb * 16 + (lane & 15);
  int cb = cc * 64 + ks2 * 32 + ((lane >> 4) * 8);
  s8v r;
#pragma unroll
  for (int j = 0; j < 8; ++j) r[j] = (short)f2bf(w[((size_t)o * 128 + cb + j) * 9 + tap]);
  *(s8v*)&wt[(size_t)id * 8] = r;
}

// ---------------- offset conv: waves = og(4) x kh(2), M=32, N=16/wave ----------------
__global__ __launch_bounds__(512, 3) void k_offconv(const unsigned short* __restrict__ xb,
                                                    const unsigned short* __restrict__ wt,
                                                    const float* __restrict__ bias,
                                                    float* __restrict__ off) {
  __shared__ char Xs[102 * 512];  // [3*34 rows][256 ch] bf16, XOR-swizzled
  __shared__ float redx[2048];    // kh pair-reduction
  int bid = blockIdx.x;
  int id8 = (bid & 7) * 64 + (bid >> 3);  // XCD swizzle (512 % 8 == 0)
  int w0 = (id8 & 1) * 32;
  int h = (id8 >> 1) & 63;
  int b = id8 >> 7;
  int t = threadIdx.x;
  int l = t & 63, wv = t >> 6;
  int og = wv & 3, kh = wv >> 2;
  f4v zero = {0.f, 0.f, 0.f, 0.f};
  f4v acc[2] = {zero, zero};

  for (int id = t; id < 3264; id += 512) {
    int tr = id >> 5, oq8 = id & 31;
    int ky = tr / 34, col = tr % 34;
    int hh = h + ky - 1, ww = w0 + col - 1;
    s8v val = {0, 0, 0, 0, 0, 0, 0, 0};
    if ((unsigned)hh < 64u && (unsigned)ww < 64u)
      val = *(const s8v*)&xb[(((size_t)(b * 64 + hh)) * 64 + ww) * 256 + oq8 * 8];
    int byte = (tr * 512 + oq8 * 16) ^ ((tr & 7) << 4);
    *(s8v*)(Xs + byte) = val;
  }
  __syncthreads();
  int khi = l >> 4, lo = l & 15;
#pragma unroll
  for (int tap = 0; tap < 9; ++tap) {
    int ky = tap / 3, kx = tap % 3;
#pragma unroll
    for (int s = 0; s < 4; ++s) {
      int cc = kh * 2 + (s >> 1);
      int ks2 = s & 1;
      int kstep = cc * 18 + tap * 2 + ks2;
      int chb = cc * 128 + ks2 * 64 + khi * 16;
      s8v bfr = *(const s8v*)&wt[((size_t)(kstep * 4 + og) * 64 + l) * 8];
#pragma unroll
      for (int m = 0; m < 2; ++m) {
        int tr = ky * 34 + m * 16 + lo + kx;
        int rbyte = (tr * 512 + chb) ^ ((tr & 7) << 4);
        s8v a = *(const s8v*)(Xs + rbyte);
        acc[m] = __builtin_amdgcn_mfma_f32_16x16x32_bf16(a, bfr, acc[m], 0, 0, 0);
      }
    }
  }
  // kh-pair reduce
  if (kh == 1) {
#pragma unroll
    for (int m = 0; m < 2; ++m)
#pragma unroll
      for (int j = 0; j < 4; ++j) redx[((og * 64 + l) * 2 + m) * 4 + j] = acc[m][j];
  }
  __syncthreads();
  if (kh == 0) {
    int o = og * 16 + lo;
    int pixb = (b * 64 + h) * 64 + w0;
    if (o < 54) {
      float bi = bias[o];
#pragma unroll
      for (int m = 0; m < 2; ++m)
#pragma unroll
        for (int j = 0; j < 4; ++j) {
          int px = pixb + m * 16 + khi * 4 + j;
          float vv = acc[m][j] + redx[((og * 64 + l) * 2 + m) * 4 + j] + bi;
          if (o >= 36) vv = 1.f / (1.f + __expf(-vv));
          off[(size_t)px * 54 + o] = vv;
        }
    }
  }
}

// ---------------- deform sample + dconv: raw-barrier pipeline (T3/T4) ----------------
#define DC_ISSUE(c, V, Q)                                   \
  do {                                                      \
    const unsigned* ip_ = sidx[(c)][px];                    \
    const float* qp_ = swt[(c)][px];                        \
    Q##0 = qp_[0]; Q##1 = qp_[1]; Q##2 = qp_[2]; Q##3 = qp_[3]; \
    V##0 = *(const s8v*)&xb[ip_[0] + chof];                 \
    V##1 = *(const s8v*)&xb[ip_[1] + chof];                 \
    V##2 = *(const s8v*)&xb[ip_[2] + chof];                 \
    V##3 = *(const s8v*)&xb[ip_[3] + chof];                 \
  } while (0)

#define DC_COMMIT(c, V, Q)                                  \
  do {                                                      \
    unsigned rr_[4];                                        \
    _Pragma("unroll") for (int jp_ = 0; jp_ < 4; ++jp_) {   \
      float f0_ = Q##0 * bf2f((unsigned short)V##0[2 * jp_]) +     \
                  Q##1 * bf2f((unsigned short)V##1[2 * jp_]) +     \
                  Q##2 * bf2f((unsigned short)V##2[2 * jp_]) +     \
                  Q##3 * bf2f((unsigned short)V##3[2 * jp_]);      \
      float f1_ = Q##0 * bf2f((unsigned short)V##0[2 * jp_ + 1]) + \
                  Q##1 * bf2f((unsigned short)V##1[2 * jp_ + 1]) + \
                  Q##2 * bf2f((unsigned short)V##2[2 * jp_ + 1]) + \
                  Q##3 * bf2f((unsigned short)V##3[2 * jp_ + 1]);  \
      unsigned p_;                                          \
      asm("v_cvt_pk_bf16_f32 %0, %1, %2" : "=v"(p_) : "v"(f0_), "v"(f1_)); \
      rr_[jp_] = p_;                                        \
    }                                                       \
    *(int4*)(&At[(c) & 1][0] + wbyte) = *(int4*)rr_;        \
  } while (0)

// light barrier: drain LDS ops only, keep global loads in flight
#define LDS_BARRIER()                                        \
  do {                                                       \
    asm volatile("s_waitcnt lgkmcnt(0)" ::: "memory");       \
    __builtin_amdgcn_s_barrier();                            \
  } while (0)

__global__ __launch_bounds__(512, 3) void k_dconv(const unsigned short* __restrict__ xb,
                                                  const float* __restrict__ off,
                                                  const unsigned short* __restrict__ wt,
                                                  float* __restrict__ y1p,
                                                  float* __restrict__ st1, float* __restrict__ st2) {
  __shared__ unsigned int sidx[18][32][4];
  __shared__ float swt[18][32][4];
  __shared__ char At[2][8192];  // [32 px][128 ch] bf16, XOR-swizzled, double-buffered
  int t = threadIdx.x;
  int l = t & 63, og = t >> 6;  // wave == o-slice
  int bid = blockIdx.x;
  int id8 = (bid & 7) * 64 + (bid >> 3);  // XCD swizzle
  int pixb = id8 * 32;
  int b = pixb >> 12, h = (pixb >> 6) & 63, w0 = pixb & 63;

  for (int id = t; id < 576; id += 512) {
    int chunk = id >> 5, ppx = id & 31;
    int g = chunk / 9, kk = chunk % 9;
    const float* op = off + (size_t)(pixb + ppx) * 54;
    float dy = op[(g * 9 + kk) * 2];
    float dx = op[(g * 9 + kk) * 2 + 1];
    float msk = op[36 + g * 9 + kk];
    float py = dy + (float)(h + kk / 3 - 1);
    float pxf = dx + (float)(w0 + ppx + kk % 3 - 1);
    float y0f = floorf(py), x0f = floorf(pxf);
    float ly = py - y0f, lx = pxf - x0f;
    int y0 = (int)y0f, x0 = (int)x0f;
    int y1 = y0 + 1, x1 = x0 + 1;
    float oky0 = (y0 >= 0 && y0 < 64) ? 1.f : 0.f;
    float oky1 = (y1 >= 0 && y1 < 64) ? 1.f : 0.f;
    float okx0 = (x0 >= 0 && x0 < 64) ? 1.f : 0.f;
    float okx1 = (x1 >= 0 && x1 < 64) ? 1.f : 0.f;
    int y0c = min(max(y0, 0), 63), y1c = min(max(y1, 0), 63);
    int x0c = min(max(x0, 0), 63), x1c = min(max(x1, 0), 63);
    unsigned base = (unsigned)(b * 4096);
    unsigned gofs = (unsigned)(g * 128);
    sidx[chunk][ppx][0] = (base + y0c * 64 + x0c) * 256u + gofs;
    sidx[chunk][ppx][1] = (base + y0c * 64 + x1c) * 256u + gofs;
    sidx[chunk][ppx][2] = (base + y1c * 64 + x0c) * 256u + gofs;
    sidx[chunk][ppx][3] = (base + y1c * 64 + x1c) * 256u + gofs;
    swt[chunk][ppx][0] = (1.f - ly) * (1.f - lx) * oky0 * okx0 * msk;
    swt[chunk][ppx][1] = (1.f - ly) * lx * oky0 * okx1 * msk;
    swt[chunk][ppx][2] = ly * (1.f - lx) * oky1 * okx0 * msk;
    swt[chunk][ppx][3] = ly * lx * oky1 * okx1 * msk;
  }
  __syncthreads();

  int px = t >> 4, oq = t & 15;
  unsigned chof = oq * 8u;
  int wbyte = (px * 256 + oq * 16) ^ ((px & 7) << 4);
  int khi = l >> 4, lo = l & 15;

  s8v va0, va1, va2, va3, vb0, vb1, vb2, vb3;
  float qa0, qa1, qa2, qa3, qb0, qb1, qb2, qb3;

  DC_ISSUE(0, va, qa);
  DC_ISSUE(1, vb, qb);
  DC_COMMIT(0, va, qa);  // waits only the 4 loads of chunk 0; chunk 1's stay in flight
  LDS_BARRIER();

  f4v zero = {0.f, 0.f, 0.f, 0.f};
  f4v acc[2] = {zero, zero};

  for (int c = 0; c < 18; ++c) {
    // issue gathers 2 chunks ahead FIRST — they stay in flight across the raw barrier
    if (c < 16) {
      if ((c & 1) == 0) DC_ISSUE(c + 2, va, qa);
      else              DC_ISSUE(c + 2, vb, qb);
    }
#pragma unroll
    for (int ks4 = 0; ks4 < 4; ++ks4) {
      int kstep = c * 4 + ks4;
      s8v bfr = *(const s8v*)&wt[((size_t)(kstep * 8 + og) * 64 + l) * 8];
      int chb = ks4 * 64 + khi * 16;
#pragma unroll
      for (int m = 0; m < 2; ++m) {
        int trA = m * 16 + lo;
        int rbyte = (trA * 256 + chb) ^ ((trA & 7) << 4);
        s8v a = *(const s8v*)(&At[c & 1][0] + rbyte);
        acc[m] = __builtin_amdgcn_mfma_f32_16x16x32_bf16(a, bfr, acc[m], 0, 0, 0);
      }
    }
    if (c < 17) {
      if ((c & 1) == 0) DC_COMMIT(c + 1, vb, qb);
      else              DC_COMMIT(c + 1, va, qa);
    }
    LDS_BARRIER();
  }

  // epilogue: y1p write + fused stats
  int o = og * 16 + lo;
  float s1v = 0.f, s2v = 0.f;
#pragma unroll
  for (int m = 0; m < 2; ++m)
#pragma unroll
    for (int j = 0; j < 4; ++j) {
      float vv = acc[m][j];
      y1p[(size_t)(pixb + m * 16 + khi * 4 + j) * 128 + o] = vv;
      s1v += vv; s2v += vv * vv;
    }
  float* red = &swt[0][0][0];
  red[khi * 128 + o] = s1v;
  red[512 + khi * 128 + o] = s2v;
  __syncthreads();
  if (t < 128) {
    float a1 = 0.f, a2 = 0.f;
#pragma unroll
    for (int rr = 0; rr < 4; ++rr) { a1 += red[rr * 128 + t]; a2 += red[512 + rr * 128 + t]; }
    atomicAdd(&st1[t], a1);
    atomicAdd(&st2[t], a2);
  }
}

// ---------------- bn1 + relu: f32 NHWC -> bf16 NHWC ----------------
__global__ __launch_bounds__(256) void k_bnrelu1(const float* __restrict__ yp, const float* __restrict__ s1,
                                                 const float* __restrict__ s2, const float* __restrict__ g,
                                                 const float* __restrict__ bb, unsigned short* __restrict__ yb) {
  __shared__ float sc[128], sh[128];
  int t = threadIdx.x;
  if (t < 128) {
    float m = s1[t] * (1.f / 16384.f);
    float var = s2[t] * (1.f / 16384.f) - m * m;
    float s = g[t] * rsqrtf(var + EPSBN);
    sc[t] = s;
    sh[t] = bb[t] - m * s;
  }
  __syncthreads();
  size_t i = ((size_t)blockIdx.x * 256 + t) * 8;
  int c0 = (int)(i & 127);
  float4 u = *(const float4*)&yp[i];
  float4 v = *(const float4*)&yp[i + 4];
  s8v r;
  r[0] = (short)f2bf(fmaxf(0.f, u.x * sc[c0 + 0] + sh[c0 + 0]));
  r[1] = (short)f2bf(fmaxf(0.f, u.y * sc[c0 + 1] + sh[c0 + 1]));
  r[2] = (short)f2bf(fmaxf(0.f, u.z * sc[c0 + 2] + sh[c0 + 2]));
  r[3] = (short)f2bf(fmaxf(0.f, u.w * sc[c0 + 3] + sh[c0 + 3]));
  r[4] = (short)f2bf(fmaxf(0.f, v.x * sc[c0 + 4] + sh[c0 + 4]));
  r[5] = (short)f2bf(fmaxf(0.f, v.y * sc[c0 + 5] + sh[c0 + 5]));
  r[6] = (short)f2bf(fmaxf(0.f, v.z * sc[c0 + 6] + sh[c0 + 6]));
  r[7] = (short)f2bf(fmaxf(0.f, v.w * sc[c0 + 7] + sh[c0 + 7]));
  *(s8v*)&yb[i] = r;
}

// ---------------- conv2: waves = og(8), M=32, fused stats ----------------
__global__ __launch_bounds__(512, 3) void k_conv2(const unsigned short* __restrict__ yb,
                                                  const unsigned short* __restrict__ wt,
                                                  float* __restrict__ y2p,
                                                  float* __restrict__ st1, float* __restrict__ st2) {
  __shared__ char Bs[102 * 256];  // [3*34 rows][128 ch] bf16, XOR-swizzled
  int bid = blockIdx.x;
  int id8 = (bid & 7) * 64 + (bid >> 3);  // XCD swizzle
  int w0 = (id8 & 1) * 32;
  int h = (id8 >> 1) & 63;
  int b = id8 >> 7;
  int t = threadIdx.x;
  int l = t & 63, og = t >> 6;
  f4v zero = {0.f, 0.f, 0.f, 0.f};
  f4v acc[2] = {zero, zero};

  for (int id = t; id < 1632; id += 512) {
    int tr = id >> 4, oq = id & 15;
    int ky = tr / 34, col = tr % 34;
    int hh = h + ky - 1, ww = w0 + col - 1;
    s8v val = {0, 0, 0, 0, 0, 0, 0, 0};
    if ((unsigned)hh < 64u && (unsigned)ww < 64u)
      val = *(const s8v*)&yb[(((size_t)(b * 64 + hh)) * 64 + ww) * 128 + oq * 8];
    int byte = (tr * 256 + oq * 16) ^ ((tr & 7) << 4);
    *(s8v*)(Bs + byte) = val;
  }
  __syncthreads();
  int khi = l >> 4, lo = l & 15;
#pragma unroll
  for (int tap = 0; tap < 9; ++tap) {
    int ky = tap / 3, kx = tap % 3;
#pragma unroll
    for (int ks4 = 0; ks4 < 4; ++ks4) {
      int kstep = ((ks4 >> 1) * 9 + tap) * 2 + (ks4 & 1);
      s8v bfr = *(const s8v*)&wt[((size_t)(kstep * 8 + og) * 64 + l) * 8];
      int chb = ks4 * 64 + khi * 16;
#pragma unroll
      for (int m = 0; m < 2; ++m) {
        int tr = ky * 34 + m * 16 + lo + kx;
        int rbyte = (tr * 256 + chb) ^ ((tr & 7) << 4);
        s8v a = *(const s8v*)(Bs + rbyte);
        acc[m] = __builtin_amdgcn_mfma_f32_16x16x32_bf16(a, bfr, acc[m], 0, 0, 0);
      }
    }
  }
  __syncthreads();  // Bs reads done before red reuse
  int pixb = (b * 64 + h) * 64 + w0;
  int o = og * 16 + lo;
  float s1v = 0.f, s2v = 0.f;
#pragma unroll
  for (int m = 0; m < 2; ++m)
#pragma unroll
    for (int j = 0; j < 4; ++j) {
      float vv = acc[m][j];
      y2p[(size_t)(pixb + m * 16 + khi * 4 + j) * 128 + o] = vv;
      s1v += vv; s2v += vv * vv;
    }
  float* red = (float*)Bs;
  red[khi * 128 + o] = s1v;
  red[512 + khi * 128 + o] = s2v;
  __syncthreads();
  if (t < 128) {
    float a1 = 0.f, a2 = 0.f;
#pragma unroll
    for (int rr = 0; rr < 4; ++rr) { a1 += red[rr * 128 + t]; a2 += red[512 + rr * 128 + t]; }
    atomicAdd(&st1[t], a1);
    atomicAdd(&st2[t], a2);
  }
}

// ---------------- bn2 + relu + NHWC -> NCHW ----------------
__global__ __launch_bounds__(256) void k_bnrelu2(const float* __restrict__ yp, const float* __restrict__ s1,
                                                 const float* __restrict__ s2, const float* __restrict__ g,
                                                 const float* __restrict__ bb, float* __restrict__ out) {
  __shared__ float sc[128], sh[128];
  int t = threadIdx.x;
  if (t < 128) {
    float m = s1[t] * (1.f / 16384.f);
    float var = s2[t] * (1.f / 16384.f) - m * m;
    float s = g[t] * rsqrtf(var + EPSBN);
    sc[t] = s;
    sh[t] = bb[t] - m * s;
  }
  __syncthreads();
  int bh = blockIdx.x;
  int b = bh >> 6, h = bh & 63;
  const float* src = yp + (size_t)bh * 64 * 128;
  for (int id = t; id < 64 * 128; id += 256) {
    int w = id & 63, o = id >> 6;
    float v = src[w * 128 + o];
    v = fmaxf(0.f, v * sc[o] + sh[o]);
    out[(((size_t)b * 128 + o) * 64 + h) * 64 + w] = v;
  }
}

extern "C" void kernel_launch(void* const* d_in, const int* in_sizes, int n_in,
                              void* d_out, int out_size, void* d_ws, size_t ws_size,
                              hipStream_t stream) {
  const float* in_v = (const float*)d_in[0];
  const float* in_i = (const float*)d_in[1];
  const float* off_w = (const float*)d_in[2];
  const float* off_b = (const float*)d_in[3];
  const float* dconv_w = (const float*)d_in[4];
  const float* bn1_g = (const float*)d_in[5];
  const float* bn1_b = (const float*)d_in[6];
  const float* conv2_w = (const float*)d_in[7];
  const float* bn2_g = (const float*)d_in[8];
  const float* bn2_b = (const float*)d_in[9];
  float* out = (float*)d_out;

  char* w = (char*)d_ws;
  unsigned short* xb = (unsigned short*)w;      w += (size_t)16384 * 256 * 2;  // 8 MB
  float* off_nhwc = (float*)w;                  w += (size_t)16384 * 54 * 4;   // 3.4 MB
  unsigned short* wtf_off = (unsigned short*)w; w += (size_t)18432 * 8 * 2;    // 288 KB
  unsigned short* wtf_d = (unsigned short*)w;   w += (size_t)36864 * 8 * 2;    // 576 KB
  unsigned short* wtf_2 = (unsigned short*)w;   w += (size_t)18432 * 8 * 2;    // 288 KB
  float* y1p = (float*)w;                       w += (size_t)16384 * 128 * 4;  // 8 MB
  unsigned short* y1b = (unsigned short*)w;     w += (size_t)16384 * 128 * 2;  // 4 MB
  float* y2p = (float*)w;                       w += (size_t)16384 * 128 * 4;  // 8 MB
  float* stats = (float*)w;                     w += 512 * 4;

  hipMemsetAsync(stats, 0, 512 * 4, stream);
  k_pack<<<dim3(128, 4, 4), dim3(32, 8), 0, stream>>>(in_v, in_i, xb);
  k_wprep_off<<<72, 256, 0, stream>>>(off_w, wtf_off);
  k_wprep_d<<<144, 256, 0, stream>>>(dconv_w, wtf_d);
  k_wprep_2<<<72, 256, 0, stream>>>(conv2_w, wtf_2);
  k_offconv<<<512, 512, 0, stream>>>(xb, wtf_off, off_b, off_nhwc);
  k_dconv<<<512, 512, 0, stream>>>(xb, off_nhwc, wtf_d, y1p, stats, stats + 128);
  k_bnrelu1<<<1024, 256, 0, stream>>>(y1p, stats, stats + 128, bn1_g, bn1_b, y1b);
  k_conv2<<<512, 512, 0, stream>>>(y1b, wtf_2, y2p, stats + 256, stats + 384);
  k_bnrelu2<<<256, 256, 0, stream>>>(y2p, stats + 256, stats + 384, bn2_g, bn2_b, out);
}